// Round 3
// baseline (1864.583 us; speedup 1.0000x reference)
//
#include <hip/hip_runtime.h>
#include <hip/hip_bf16.h>
#include <cstddef>

using bf16 = __hip_bfloat16;

#define NPIX 65536  // 256*256

static __device__ __forceinline__ float b2f(bf16 v) { return __bfloat162float(v); }
static __device__ __forceinline__ bf16  f2b(float v) { return __float2bfloat16(v); }

// ---------------- per-pixel LN stats: mu, rstd over 64 channels ----------------
__global__ void k_stats(const float* __restrict__ in, float* __restrict__ mu,
                        float* __restrict__ rs) {
  int pi = blockIdx.x * 256 + threadIdx.x;      // 0 .. B*N-1
  int b = pi >> 16, n = pi & 65535;
  const float* p = in + ((size_t)b << 22) + n;
  float s = 0.f, s2 = 0.f;
  #pragma unroll
  for (int c = 0; c < 64; ++c) {
    float v = p[(size_t)c << 16];
    s += v; s2 += v * v;
  }
  float m = s * 0.015625f;
  float var = s2 * 0.015625f - m * m;
  mu[pi] = m;
  rs[pi] = rsqrtf(var + 1e-5f);
}

// ---------------- xg[b][c] = mean over pixels of LN output ----------------
__global__ void k_xg(const float* __restrict__ in, const float* __restrict__ mu,
                     const float* __restrict__ rs, const float* __restrict__ w,
                     const float* __restrict__ bias, float* __restrict__ xg) {
  int bc = blockIdx.x;                           // 0..255  (b*64+c)
  int b = bc >> 6, c = bc & 63;
  const float* p = in + ((size_t)bc << 16);
  const float* mup = mu + (b << 16);
  const float* rsp = rs + (b << 16);
  float s = 0.f;
  for (int i = threadIdx.x; i < NPIX; i += 256)
    s += (p[i] - mup[i]) * rsp[i];
  #pragma unroll
  for (int o = 32; o > 0; o >>= 1) s += __shfl_down(s, o, 64);
  __shared__ float red[4];
  if ((threadIdx.x & 63) == 0) red[threadIdx.x >> 6] = s;
  __syncthreads();
  if (threadIdx.x == 0)
    xg[bc] = (red[0] + red[1] + red[2] + red[3]) * (1.f / 65536.f) * w[c] + bias[c];
}

__global__ void k_zero(float* __restrict__ p, int n) {
  int i = blockIdx.x * 256 + threadIdx.x;
  if (i < n) p[i] = 0.f;
}

// ---------------- Gram matrix M[b] = ln1 @ ln1^T  (64x64 per batch), LN inline ----------------
__global__ void k_M(const float* __restrict__ x, const float* __restrict__ mu,
                    const float* __restrict__ rs, const float* __restrict__ w,
                    const float* __restrict__ bias, float* __restrict__ M) {
  int b = blockIdx.x >> 6;
  int n0 = (blockIdx.x & 63) << 10;              // 1024 pixels per block
  __shared__ float tile[64][68];
  int ti = threadIdx.x >> 4, tj = threadIdx.x & 15;
  float acc[4][4] = {};
  for (int t0 = 0; t0 < 1024; t0 += 64) {
    __syncthreads();
    for (int idx = threadIdx.x; idx < 4096; idx += 256) {
      int ch = idx >> 6, px = idx & 63;
      int n = n0 + t0 + px;
      float xv = x[((size_t)(b * 64 + ch) << 16) + n];
      tile[ch][px] = (xv - mu[(b << 16) + n]) * rs[(b << 16) + n] * w[ch] + bias[ch];
    }
    __syncthreads();
    #pragma unroll 4
    for (int p = 0; p < 64; p += 4) {
      float4 av[4], bv[4];
      #pragma unroll
      for (int i = 0; i < 4; ++i) av[i] = *(const float4*)&tile[4 * ti + i][p];
      #pragma unroll
      for (int j = 0; j < 4; ++j) bv[j] = *(const float4*)&tile[4 * tj + j][p];
      #pragma unroll
      for (int i = 0; i < 4; ++i)
        #pragma unroll
        for (int j = 0; j < 4; ++j)
          acc[i][j] += av[i].x * bv[j].x + av[i].y * bv[j].y +
                       av[i].z * bv[j].z + av[i].w * bv[j].w;
    }
  }
  #pragma unroll
  for (int i = 0; i < 4; ++i)
    #pragma unroll
    for (int j = 0; j < 4; ++j)
      atomicAdd(&M[b * 4096 + (4 * ti + i) * 64 + (4 * tj + j)], acc[i][j]);
}

// ---------------- routing: h1 = gelu(W1 @ [xg;hid] + b1); logit = relu(W3 @ h1 + b3) ----------------
__global__ void k_route(const float* __restrict__ xg, const float* __restrict__ hid,
                        const float* __restrict__ w1, const float* __restrict__ b1,
                        const float* __restrict__ w3, const float* __restrict__ b3,
                        float* __restrict__ h1_out, float* __restrict__ logit_out,
                        float* __restrict__ out_logits, int slot,
                        float* __restrict__ out_hidden) {
  __shared__ float h1s[4][16];
  int t = threadIdx.x;
  if (t < 64) {
    int b = t >> 4, j = t & 15;
    float a = b1[j];
    for (int c = 0; c < 64; ++c) a += w1[j * 80 + c] * xg[b * 64 + c];
    for (int k = 0; k < 16; ++k) a += w1[j * 80 + 64 + k] * hid[b * 16 + k];
    float g = 0.5f * a * (1.f + erff(a * 0.70710678f));   // exact gelu
    h1s[b][j] = g;
    h1_out[b * 16 + j] = g;
    if (out_hidden) out_hidden[b * 16 + j] = g;
  }
  __syncthreads();
  if (t < 12) {
    int b = t / 3, e = t % 3;
    float a = b3[e];
    for (int j = 0; j < 16; ++j) a += w3[e * 16 + j] * h1s[b][j];
    a = fmaxf(a, 0.f);
    logit_out[b * 3 + e] = a;
    out_logits[b * 6 + e * 2 + slot] = a;
  }
}

// ---------------- per (b,expert): softmax(q̂·k̂·temp) -> Weff = P @ Wv ----------------
__global__ void k_expw(const float* __restrict__ M, const float* __restrict__ qkv,
                       const float* __restrict__ temp, float* __restrict__ Weff) {
  int b = blockIdx.x / 3, e = blockIdx.x % 3;
  __shared__ float Ms[64][64];
  __shared__ float TQ[64][64];
  __shared__ float TK[64][64];
  __shared__ float P[64][4];
  __shared__ float nq[64], nk[64];
  const float* W = qkv + e * 12288;              // (192,64) for this expert
  for (int idx = threadIdx.x; idx < 4096; idx += 256)
    Ms[idx >> 6][idx & 63] = M[b * 4096 + idx];
  __syncthreads();
  {
    int r = threadIdx.x >> 2;
    int v0 = (threadIdx.x & 3) << 4;
    float aq[16] = {}, ak[16] = {};
    for (int u = 0; u < 64; ++u) {
      float wq = W[r * 64 + u];                  // q row r
      float wk = W[(64 + r) * 64 + u];           // k row r
      #pragma unroll
      for (int i = 0; i < 16; ++i) {
        float m = Ms[u][v0 + i];
        aq[i] += wq * m; ak[i] += wk * m;
      }
    }
    #pragma unroll
    for (int i = 0; i < 16; ++i) { TQ[r][v0 + i] = aq[i]; TK[r][v0 + i] = ak[i]; }
  }
  __syncthreads();
  if (threadIdx.x < 64) {
    int c = threadIdx.x;
    float sq = 0.f, sk = 0.f;
    for (int v = 0; v < 64; ++v) {
      sq += TQ[c][v] * W[c * 64 + v];
      sk += TK[c][v] * W[(64 + c) * 64 + v];
    }
    nq[c] = fmaxf(sqrtf(fmaxf(sq, 0.f)), 1e-12f);
    nk[c] = fmaxf(sqrtf(fmaxf(sk, 0.f)), 1e-12f);
  }
  __syncthreads();
  if (threadIdx.x < 64) {
    int rr = threadIdx.x, h = rr >> 2;
    float tp = temp[e * 16 + h];
    float s[4];
    #pragma unroll
    for (int d = 0; d < 4; ++d) {
      int kc = h * 4 + d;
      float g = 0.f;
      for (int v = 0; v < 64; ++v) g += TQ[rr][v] * W[(64 + kc) * 64 + v];
      s[d] = g / (nq[rr] * nk[kc]) * tp;
    }
    float mx = fmaxf(fmaxf(s[0], s[1]), fmaxf(s[2], s[3]));
    float es[4], sum = 0.f;
    #pragma unroll
    for (int d = 0; d < 4; ++d) { es[d] = __expf(s[d] - mx); sum += es[d]; }
    float inv = 1.f / sum;
    #pragma unroll
    for (int d = 0; d < 4; ++d) P[rr][d] = es[d] * inv;
  }
  __syncthreads();
  if (threadIdx.x < 64) {
    int rr = threadIdx.x, h = rr >> 2;
    for (int u = 0; u < 64; ++u) {
      float a = 0.f;
      #pragma unroll
      for (int d = 0; d < 4; ++d)
        a += P[rr][d] * W[(128 + h * 4 + d) * 64 + u];
      Weff[(size_t)(b * 3 + e) * 4096 + rr * 64 + u] = a;
    }
  }
}

// ---------------- Kt[b][tap][u][o] = Σ_e l1_e Proj_e[o,c] dw_e[c,tap] Weff_e[c,u] ----------------
__global__ void k_kmat(const float* __restrict__ Weff, const float* __restrict__ dw,
                       const float* __restrict__ proj, const float* __restrict__ l1,
                       float* __restrict__ Kt) {
  int b = blockIdx.x / 9, t = blockIdx.x % 9;
  __shared__ float S[64][68];
  __shared__ float Pr[64][68];
  int u = threadIdx.x >> 2, o0 = (threadIdx.x & 3) << 4;
  float acc[16] = {};
  for (int e = 0; e < 3; ++e) {
    __syncthreads();
    float le = l1[b * 3 + e];
    for (int idx = threadIdx.x; idx < 4096; idx += 256) {
      int c = idx >> 6, uu = idx & 63;
      S[c][uu] = le * dw[(e * 64 + c) * 9 + t] *
                 Weff[(size_t)(b * 3 + e) * 4096 + c * 64 + uu];
      Pr[c][uu] = proj[e * 4096 + uu * 64 + c];  // Pr[c][o] = proj[o,c]
    }
    __syncthreads();
    for (int c = 0; c < 64; ++c) {
      float sv = S[c][u];
      #pragma unroll
      for (int i = 0; i < 16; ++i) acc[i] += Pr[c][o0 + i] * sv;
    }
  }
  #pragma unroll
  for (int i = 0; i < 16; ++i)
    Kt[(size_t)(b * 9 + t) * 4096 + u * 64 + o0 + i] = acc[i];
}

// ---------------- collapsed attention bank: out1 = Conv3x3(ln1(x); Kt[b]) + beta*x ----------------
__global__ void k_conv(const float* __restrict__ x, const float* __restrict__ mu,
                       const float* __restrict__ rs, const float* __restrict__ lw,
                       const float* __restrict__ lb, const float* __restrict__ Kt,
                       const float* __restrict__ beta, float* __restrict__ out1) {
  __shared__ bf16 hl[64 * 332];                  // 64ch x 18x18 halo (pad 324->332)
  int x0 = blockIdx.x << 4, y0 = blockIdx.y << 4, b = blockIdx.z;
  for (int idx = threadIdx.x; idx < 20736; idx += 256) {
    int u = idx / 324, r2 = idx - u * 324;
    int sy = r2 / 18, sx = r2 - sy * 18;
    int gy = y0 + sy - 1, gx = x0 + sx - 1;
    float v = 0.f;
    if ((unsigned)gy < 256u && (unsigned)gx < 256u) {
      int n = (gy << 8) + gx;
      float xv = x[((size_t)(b * 64 + u) << 16) + n];
      v = (xv - mu[(b << 16) + n]) * rs[(b << 16) + n] * lw[u] + lb[u];
    }
    hl[u * 332 + sy * 18 + sx] = f2b(v);
  }
  __syncthreads();
  int sy = threadIdx.x >> 4, sx = threadIdx.x & 15;
  int n = ((y0 + sy) << 8) + x0 + sx;
  float acc[64];
  #pragma unroll
  for (int o = 0; o < 64; ++o)
    acc[o] = beta[o] * x[((size_t)(b * 64 + o) << 16) + n];
  const float* Kb = Kt + (size_t)b * 36864;
  #pragma unroll
  for (int ky = 0; ky < 3; ++ky)
    #pragma unroll
    for (int kx = 0; kx < 3; ++kx) {
      const float* Ktap = Kb + ((ky * 3 + kx) << 12);
      int base = (sy + ky) * 18 + sx + kx;
      for (int u = 0; u < 64; ++u) {
        float xv = b2f(hl[u * 332 + base]);
        const float* Ko = Ktap + (u << 6);       // weights uniform -> scalar loads
        #pragma unroll
        for (int o = 0; o < 64; ++o) acc[o] += Ko[o] * xv;
      }
    }
  #pragma unroll
  for (int o = 0; o < 64; ++o)
    out1[((size_t)(b * 64 + o) << 16) + n] = acc[o];
}

// ---------------- gather MLP weights: w1/b1 concat, w2 transposed ----------------
__global__ void k_prep(const float* __restrict__ w1_0, const float* __restrict__ w1_1,
                       const float* __restrict__ w1_2,
                       const float* __restrict__ b1_0, const float* __restrict__ b1_1,
                       const float* __restrict__ b1_2,
                       const float* __restrict__ w2_0, const float* __restrict__ w2_1,
                       const float* __restrict__ w2_2,
                       float* __restrict__ w1f, float* __restrict__ w2tf,
                       float* __restrict__ b1f) {
  int idx = blockIdx.x * 256 + threadIdx.x;      // 112*256 = 28672 = 448*64
  if (idx >= 448 * 64) return;
  int jt = idx >> 6, c = idx & 63;
  int e, j;
  if (jt < 64)       { e = 0; j = jt; }
  else if (jt < 192) { e = 1; j = jt - 64; }
  else               { e = 2; j = jt - 192; }
  const float* w1 = e == 0 ? w1_0 : (e == 1 ? w1_1 : w1_2);
  const float* w2 = e == 0 ? w2_0 : (e == 1 ? w2_1 : w2_2);
  int hf = 64 << e;
  w1f[idx]  = w1[j * 64 + c];                    // [jt][c]
  w2tf[idx] = w2[c * hf + j];                    // [jt][o]
  if (c == 0) {
    const float* b1 = e == 0 ? b1_0 : (e == 1 ? b1_1 : b1_2);
    b1f[jt] = b1[j];
  }
}

// ---------------- fused MLP bank over io buffer (out1 in, final out over same) ----------------
__global__ void k_mlp(float* io,                     // aliased read+write, per-thread safe
                      const float* __restrict__ mu2, const float* __restrict__ rs2,
                      const float* __restrict__ lw, const float* __restrict__ lb,
                      const float* __restrict__ w1f, const float* __restrict__ w2tf,
                      const float* __restrict__ b1f,
                      const float* __restrict__ b2_0, const float* __restrict__ b2_1,
                      const float* __restrict__ b2_2,
                      const float* __restrict__ gamma, const float* __restrict__ l2) {
  int pi = blockIdx.x * 256 + threadIdx.x;
  int b = pi >> 16, n = pi & 65535;
  float l2v0 = l2[b * 3], l2v1 = l2[b * 3 + 1], l2v2 = l2[b * 3 + 2];
  float m = mu2[pi], r = rs2[pi];
  size_t base = ((size_t)b << 22) + n;
  float xv[64];
  float acc[64];
  #pragma unroll
  for (int c = 0; c < 64; ++c) {
    float o1 = io[base + ((size_t)c << 16)];
    xv[c] = (o1 - m) * r * lw[c] + lb[c];
    acc[c] = gamma[c] * o1 + l2v0 * b2_0[c] + l2v1 * b2_1[c] + l2v2 * b2_2[c];
  }
  int jt = 0;
  for (int e = 0; e < 3; ++e) {
    int hf = 64 << e;
    float le = (e == 0) ? l2v0 : (e == 1 ? l2v1 : l2v2);
    for (int j = 0; j < hf; ++j, ++jt) {
      const float* wr = w1f + (jt << 6);
      float t = b1f[jt];
      #pragma unroll
      for (int c = 0; c < 64; ++c) t += wr[c] * xv[c];
      float g = le * 0.5f * t * (1.f + erff(t * 0.70710678f));  // exact gelu
      const float* w2r = w2tf + (jt << 6);
      #pragma unroll
      for (int o = 0; o < 64; ++o) acc[o] += w2r[o] * g;
    }
  }
  #pragma unroll
  for (int o = 0; o < 64; ++o)
    io[base + ((size_t)o << 16)] = acc[o];
}

extern "C" void kernel_launch(void* const* d_in, const int* in_sizes, int n_in,
                              void* d_out, int out_size, void* d_ws, size_t ws_size,
                              hipStream_t stream) {
  (void)in_sizes; (void)n_in; (void)out_size; (void)ws_size;
  const float* x        = (const float*)d_in[0];
  const float* hidden   = (const float*)d_in[1];
  const float* ln1_w    = (const float*)d_in[2];
  const float* ln1_b    = (const float*)d_in[3];
  const float* ln2_w    = (const float*)d_in[4];
  const float* ln2_b    = (const float*)d_in[5];
  const float* beta     = (const float*)d_in[6];
  const float* gamma    = (const float*)d_in[7];
  const float* att_temp = (const float*)d_in[8];
  const float* att_qkv  = (const float*)d_in[9];
  const float* att_dw   = (const float*)d_in[10];
  const float* att_proj = (const float*)d_in[11];
  const float* ar1_w    = (const float*)d_in[12];
  const float* ar1_b    = (const float*)d_in[13];
  const float* ar3_w    = (const float*)d_in[14];
  const float* ar3_b    = (const float*)d_in[15];
  const float* mr1_w    = (const float*)d_in[16];
  const float* mr1_b    = (const float*)d_in[17];
  const float* mr3_w    = (const float*)d_in[18];
  const float* mr3_b    = (const float*)d_in[19];
  const float* w1s[3] = {(const float*)d_in[20], (const float*)d_in[24], (const float*)d_in[28]};
  const float* b1s[3] = {(const float*)d_in[21], (const float*)d_in[25], (const float*)d_in[29]};
  const float* w2s[3] = {(const float*)d_in[22], (const float*)d_in[26], (const float*)d_in[30]};
  const float* b2s[3] = {(const float*)d_in[23], (const float*)d_in[27], (const float*)d_in[31]};

  // ---- workspace: ~5.3 MB of fp32 only ----
  float* F    = (float*)d_ws;
  float* mu1  = F + 0;          // 262144
  float* rs1  = F + 262144;     // 262144
  float* mu2  = F + 524288;     // 262144
  float* rs2  = F + 786432;     // 262144
  float* xg1  = F + 1048576;    // 256
  float* xg2  = F + 1048832;    // 256
  float* M    = F + 1049088;    // 16384
  float* h1a  = F + 1065472;    // 64
  float* h1m  = F + 1065536;    // 64
  float* l1   = F + 1065600;    // 16
  float* l2   = F + 1065616;    // 16
  float* Weff = F + 1065632;    // 49152
  float* Kt   = F + 1114784;    // 147456
  float* w1f  = F + 1262240;    // 28672
  float* w2tf = F + 1290912;    // 28672
  float* b1f  = F + 1319584;    // 448  -> total 1,320,032 floats = 5.28 MB

  float* out_main   = (float*)d_out;             // also holds out1 between banks
  float* out_hidden = out_main + 16777216;
  float* out_logits = out_main + 16777280;

  // ---- attention bank ----
  k_stats<<<1024, 256, 0, stream>>>(x, mu1, rs1);
  k_xg   <<<256, 256, 0, stream>>>(x, mu1, rs1, ln1_w, ln1_b, xg1);
  k_zero <<<64, 256, 0, stream>>>(M, 16384);
  k_M    <<<256, 256, 0, stream>>>(x, mu1, rs1, ln1_w, ln1_b, M);
  k_route<<<1, 64, 0, stream>>>(xg1, hidden, ar1_w, ar1_b, ar3_w, ar3_b,
                                h1a, l1, out_logits, 0, nullptr);
  k_expw <<<12, 256, 0, stream>>>(M, att_qkv, att_temp, Weff);
  k_kmat <<<36, 256, 0, stream>>>(Weff, att_dw, att_proj, l1, Kt);
  k_conv <<<dim3(16, 16, 4), 256, 0, stream>>>(x, mu1, rs1, ln1_w, ln1_b, Kt,
                                               beta, out_main);
  // ---- MLP bank (out1 lives in d_out) ----
  k_stats<<<1024, 256, 0, stream>>>(out_main, mu2, rs2);
  k_xg   <<<256, 256, 0, stream>>>(out_main, mu2, rs2, ln2_w, ln2_b, xg2);
  k_route<<<1, 64, 0, stream>>>(xg2, h1a, mr1_w, mr1_b, mr3_w, mr3_b,
                                h1m, l2, out_logits, 1, out_hidden);
  k_prep <<<112, 256, 0, stream>>>(w1s[0], w1s[1], w1s[2], b1s[0], b1s[1], b1s[2],
                                   w2s[0], w2s[1], w2s[2], w1f, w2tf, b1f);
  k_mlp  <<<1024, 256, 0, stream>>>(out_main, mu2, rs2, ln2_w, ln2_b,
                                    w1f, w2tf, b1f, b2s[0], b2s[1], b2s[2],
                                    gamma, l2);
}

// Round 4
// 938.539 us; speedup vs baseline: 1.9867x; 1.9867x over previous
//
#include <hip/hip_runtime.h>
#include <hip/hip_bf16.h>
#include <cstddef>

using bf16 = __hip_bfloat16;
typedef __attribute__((ext_vector_type(8))) short short8;
typedef __attribute__((ext_vector_type(4))) float f32x4;

#define NPIX 65536  // 256*256

static __device__ __forceinline__ float b2f(bf16 v) { return __bfloat162float(v); }
static __device__ __forceinline__ bf16  f2b(float v) { return __float2bfloat16(v); }
static __device__ __forceinline__ unsigned short f2bs(float f) {
  union { float f; unsigned u; } v; v.f = f;
  unsigned r = (v.u + 0x7FFFu + ((v.u >> 16) & 1u)) >> 16;
  return (unsigned short)r;
}

// ---------------- per-pixel LN stats: mu, rstd over 64 channels ----------------
__global__ void k_stats(const float* __restrict__ in, float* __restrict__ mu,
                        float* __restrict__ rs) {
  int pi = blockIdx.x * 256 + threadIdx.x;      // 0 .. B*N-1
  int b = pi >> 16, n = pi & 65535;
  const float* p = in + ((size_t)b << 22) + n;
  float s = 0.f, s2 = 0.f;
  #pragma unroll
  for (int c = 0; c < 64; ++c) {
    float v = p[(size_t)c << 16];
    s += v; s2 += v * v;
  }
  float m = s * 0.015625f;
  float var = s2 * 0.015625f - m * m;
  mu[pi] = m;
  rs[pi] = rsqrtf(var + 1e-5f);
}

// ---------------- xg[b][c] = mean over pixels of LN output ----------------
__global__ void k_xg(const float* __restrict__ in, const float* __restrict__ mu,
                     const float* __restrict__ rs, const float* __restrict__ w,
                     const float* __restrict__ bias, float* __restrict__ xg) {
  int bc = blockIdx.x;                           // 0..255  (b*64+c)
  int b = bc >> 6, c = bc & 63;
  const float* p = in + ((size_t)bc << 16);
  const float* mup = mu + (b << 16);
  const float* rsp = rs + (b << 16);
  float s = 0.f;
  for (int i = threadIdx.x; i < NPIX; i += 256)
    s += (p[i] - mup[i]) * rsp[i];
  #pragma unroll
  for (int o = 32; o > 0; o >>= 1) s += __shfl_down(s, o, 64);
  __shared__ float red[4];
  if ((threadIdx.x & 63) == 0) red[threadIdx.x >> 6] = s;
  __syncthreads();
  if (threadIdx.x == 0)
    xg[bc] = (red[0] + red[1] + red[2] + red[3]) * (1.f / 65536.f) * w[c] + bias[c];
}

__global__ void k_zero(float* __restrict__ p, int n) {
  int i = blockIdx.x * 256 + threadIdx.x;
  if (i < n) p[i] = 0.f;
}

// ---------------- Gram matrix M[b] = ln1 @ ln1^T  (64x64 per batch), LN inline ----------------
__global__ void k_M(const float* __restrict__ x, const float* __restrict__ mu,
                    const float* __restrict__ rs, const float* __restrict__ w,
                    const float* __restrict__ bias, float* __restrict__ M) {
  int b = blockIdx.x >> 6;
  int n0 = (blockIdx.x & 63) << 10;              // 1024 pixels per block
  __shared__ float tile[64][68];
  int ti = threadIdx.x >> 4, tj = threadIdx.x & 15;
  float acc[4][4] = {};
  for (int t0 = 0; t0 < 1024; t0 += 64) {
    __syncthreads();
    for (int idx = threadIdx.x; idx < 4096; idx += 256) {
      int ch = idx >> 6, px = idx & 63;
      int n = n0 + t0 + px;
      float xv = x[((size_t)(b * 64 + ch) << 16) + n];
      tile[ch][px] = (xv - mu[(b << 16) + n]) * rs[(b << 16) + n] * w[ch] + bias[ch];
    }
    __syncthreads();
    #pragma unroll 4
    for (int p = 0; p < 64; p += 4) {
      float4 av[4], bv[4];
      #pragma unroll
      for (int i = 0; i < 4; ++i) av[i] = *(const float4*)&tile[4 * ti + i][p];
      #pragma unroll
      for (int j = 0; j < 4; ++j) bv[j] = *(const float4*)&tile[4 * tj + j][p];
      #pragma unroll
      for (int i = 0; i < 4; ++i)
        #pragma unroll
        for (int j = 0; j < 4; ++j)
          acc[i][j] += av[i].x * bv[j].x + av[i].y * bv[j].y +
                       av[i].z * bv[j].z + av[i].w * bv[j].w;
    }
  }
  #pragma unroll
  for (int i = 0; i < 4; ++i)
    #pragma unroll
    for (int j = 0; j < 4; ++j)
      atomicAdd(&M[b * 4096 + (4 * ti + i) * 64 + (4 * tj + j)], acc[i][j]);
}

// ---------------- routing ----------------
__global__ void k_route(const float* __restrict__ xg, const float* __restrict__ hid,
                        const float* __restrict__ w1, const float* __restrict__ b1,
                        const float* __restrict__ w3, const float* __restrict__ b3,
                        float* __restrict__ h1_out, float* __restrict__ logit_out,
                        float* __restrict__ out_logits, int slot,
                        float* __restrict__ out_hidden) {
  __shared__ float h1s[4][16];
  int t = threadIdx.x;
  if (t < 64) {
    int b = t >> 4, j = t & 15;
    float a = b1[j];
    for (int c = 0; c < 64; ++c) a += w1[j * 80 + c] * xg[b * 64 + c];
    for (int k = 0; k < 16; ++k) a += w1[j * 80 + 64 + k] * hid[b * 16 + k];
    float g = 0.5f * a * (1.f + erff(a * 0.70710678f));   // exact gelu
    h1s[b][j] = g;
    h1_out[b * 16 + j] = g;
    if (out_hidden) out_hidden[b * 16 + j] = g;
  }
  __syncthreads();
  if (t < 12) {
    int b = t / 3, e = t % 3;
    float a = b3[e];
    for (int j = 0; j < 16; ++j) a += w3[e * 16 + j] * h1s[b][j];
    a = fmaxf(a, 0.f);
    logit_out[b * 3 + e] = a;
    out_logits[b * 6 + e * 2 + slot] = a;
  }
}

// ---------------- per (b,expert): softmax(q̂·k̂·temp) -> Weff = P @ Wv ----------------
__global__ void k_expw(const float* __restrict__ M, const float* __restrict__ qkv,
                       const float* __restrict__ temp, float* __restrict__ Weff) {
  int b = blockIdx.x / 3, e = blockIdx.x % 3;
  __shared__ float Ms[64][64];
  __shared__ float TQ[64][64];
  __shared__ float TK[64][64];
  __shared__ float P[64][4];
  __shared__ float nq[64], nk[64];
  const float* W = qkv + e * 12288;              // (192,64) for this expert
  for (int idx = threadIdx.x; idx < 4096; idx += 256)
    Ms[idx >> 6][idx & 63] = M[b * 4096 + idx];
  __syncthreads();
  {
    int r = threadIdx.x >> 2;
    int v0 = (threadIdx.x & 3) << 4;
    float aq[16] = {}, ak[16] = {};
    for (int u = 0; u < 64; ++u) {
      float wq = W[r * 64 + u];
      float wk = W[(64 + r) * 64 + u];
      #pragma unroll
      for (int i = 0; i < 16; ++i) {
        float m = Ms[u][v0 + i];
        aq[i] += wq * m; ak[i] += wk * m;
      }
    }
    #pragma unroll
    for (int i = 0; i < 16; ++i) { TQ[r][v0 + i] = aq[i]; TK[r][v0 + i] = ak[i]; }
  }
  __syncthreads();
  if (threadIdx.x < 64) {
    int c = threadIdx.x;
    float sq = 0.f, sk = 0.f;
    for (int v = 0; v < 64; ++v) {
      sq += TQ[c][v] * W[c * 64 + v];
      sk += TK[c][v] * W[(64 + c) * 64 + v];
    }
    nq[c] = fmaxf(sqrtf(fmaxf(sq, 0.f)), 1e-12f);
    nk[c] = fmaxf(sqrtf(fmaxf(sk, 0.f)), 1e-12f);
  }
  __syncthreads();
  if (threadIdx.x < 64) {
    int rr = threadIdx.x, h = rr >> 2;
    float tp = temp[e * 16 + h];
    float s[4];
    #pragma unroll
    for (int d = 0; d < 4; ++d) {
      int kc = h * 4 + d;
      float g = 0.f;
      for (int v = 0; v < 64; ++v) g += TQ[rr][v] * W[(64 + kc) * 64 + v];
      s[d] = g / (nq[rr] * nk[kc]) * tp;
    }
    float mx = fmaxf(fmaxf(s[0], s[1]), fmaxf(s[2], s[3]));
    float es[4], sum = 0.f;
    #pragma unroll
    for (int d = 0; d < 4; ++d) { es[d] = __expf(s[d] - mx); sum += es[d]; }
    float inv = 1.f / sum;
    #pragma unroll
    for (int d = 0; d < 4; ++d) P[rr][d] = es[d] * inv;
  }
  __syncthreads();
  if (threadIdx.x < 64) {
    int rr = threadIdx.x, h = rr >> 2;
    for (int u = 0; u < 64; ++u) {
      float a = 0.f;
      #pragma unroll
      for (int d = 0; d < 4; ++d)
        a += P[rr][d] * W[(128 + h * 4 + d) * 64 + u];
      Weff[(size_t)(b * 3 + e) * 4096 + rr * 64 + u] = a;
    }
  }
}

// ---------------- Kt[b][tap][u][o] = Σ_e l1_e Proj_e[o,c] dw_e[c,tap] Weff_e[c,u] ----------------
__global__ void k_kmat(const float* __restrict__ Weff, const float* __restrict__ dw,
                       const float* __restrict__ proj, const float* __restrict__ l1,
                       float* __restrict__ Kt) {
  int b = blockIdx.x / 9, t = blockIdx.x % 9;
  __shared__ float S[64][68];
  __shared__ float Pr[64][68];
  int u = threadIdx.x >> 2, o0 = (threadIdx.x & 3) << 4;
  float acc[16] = {};
  for (int e = 0; e < 3; ++e) {
    __syncthreads();
    float le = l1[b * 3 + e];
    for (int idx = threadIdx.x; idx < 4096; idx += 256) {
      int c = idx >> 6, uu = idx & 63;
      S[c][uu] = le * dw[(e * 64 + c) * 9 + t] *
                 Weff[(size_t)(b * 3 + e) * 4096 + c * 64 + uu];
      Pr[c][uu] = proj[e * 4096 + uu * 64 + c];
    }
    __syncthreads();
    for (int c = 0; c < 64; ++c) {
      float sv = S[c][u];
      #pragma unroll
      for (int i = 0; i < 16; ++i) acc[i] += Pr[c][o0 + i] * sv;
    }
  }
  #pragma unroll
  for (int i = 0; i < 16; ++i)
    Kt[(size_t)(b * 9 + t) * 4096 + u * 64 + o0 + i] = acc[i];
}

// ---------------- collapsed attention bank: out1 = Conv3x3(ln1(x); Kt[b]) + beta*x ----------------
__global__ void k_conv(const float* __restrict__ x, const float* __restrict__ mu,
                       const float* __restrict__ rs, const float* __restrict__ lw,
                       const float* __restrict__ lb, const float* __restrict__ Kt,
                       const float* __restrict__ beta, float* __restrict__ out1) {
  __shared__ bf16 hl[64 * 332];                  // 64ch x 18x18 halo (pad 324->332)
  int x0 = blockIdx.x << 4, y0 = blockIdx.y << 4, b = blockIdx.z;
  for (int idx = threadIdx.x; idx < 20736; idx += 256) {
    int u = idx / 324, r2 = idx - u * 324;
    int sy = r2 / 18, sx = r2 - sy * 18;
    int gy = y0 + sy - 1, gx = x0 + sx - 1;
    float v = 0.f;
    if ((unsigned)gy < 256u && (unsigned)gx < 256u) {
      int n = (gy << 8) + gx;
      float xv = x[((size_t)(b * 64 + u) << 16) + n];
      v = (xv - mu[(b << 16) + n]) * rs[(b << 16) + n] * lw[u] + lb[u];
    }
    hl[u * 332 + sy * 18 + sx] = f2b(v);
  }
  __syncthreads();
  int sy = threadIdx.x >> 4, sx = threadIdx.x & 15;
  int n = ((y0 + sy) << 8) + x0 + sx;
  float acc[64];
  #pragma unroll
  for (int o = 0; o < 64; ++o)
    acc[o] = beta[o] * x[((size_t)(b * 64 + o) << 16) + n];
  const float* Kb = Kt + (size_t)b * 36864;
  #pragma unroll
  for (int ky = 0; ky < 3; ++ky)
    #pragma unroll
    for (int kx = 0; kx < 3; ++kx) {
      const float* Ktap = Kb + ((ky * 3 + kx) << 12);
      int base = (sy + ky) * 18 + sx + kx;
      for (int u = 0; u < 64; ++u) {
        float xv = b2f(hl[u * 332 + base]);
        const float* Ko = Ktap + (u << 6);
        #pragma unroll
        for (int o = 0; o < 64; ++o) acc[o] += Ko[o] * xv;
      }
    }
  #pragma unroll
  for (int o = 0; o < 64; ++o)
    out1[((size_t)(b * 64 + o) << 16) + n] = acc[o];
}

// ---------------- prep MLP weights as bf16: w1b[jt][c], w2b[o][jt], b1f[jt] ----------------
__global__ void k_prep(const float* __restrict__ w1_0, const float* __restrict__ w1_1,
                       const float* __restrict__ w1_2,
                       const float* __restrict__ b1_0, const float* __restrict__ b1_1,
                       const float* __restrict__ b1_2,
                       const float* __restrict__ w2_0, const float* __restrict__ w2_1,
                       const float* __restrict__ w2_2,
                       unsigned short* __restrict__ w1b, unsigned short* __restrict__ w2b,
                       float* __restrict__ b1f) {
  int idx = blockIdx.x * 256 + threadIdx.x;      // 112*256 = 28672 = 448*64
  if (idx >= 448 * 64) return;
  int jt = idx >> 6, c = idx & 63;
  int e, j;
  if (jt < 64)       { e = 0; j = jt; }
  else if (jt < 192) { e = 1; j = jt - 64; }
  else               { e = 2; j = jt - 192; }
  const float* w1 = e == 0 ? w1_0 : (e == 1 ? w1_1 : w1_2);
  const float* w2 = e == 0 ? w2_0 : (e == 1 ? w2_1 : w2_2);
  int hf = 64 << e;
  w1b[jt * 64 + c]  = f2bs(w1[j * 64 + c]);
  w2b[c * 448 + jt] = f2bs(w2[c * hf + j]);
  if (c == 0) {
    const float* b1 = e == 0 ? b1_0 : (e == 1 ? b1_1 : b1_2);
    b1f[jt] = b1[j];
  }
}

// ---------------- MFMA fused MLP bank: io = Σ_e l2_e MLP_e(ln2(io)) + gamma*io ----------------
// block: 512 thr (8 waves), 128 pixels; wave w owns pixels [16w,16w+16)
__global__ __launch_bounds__(512, 2)
void k_mlp(float* io,
           const float* __restrict__ mu2, const float* __restrict__ rs2,
           const float* __restrict__ lw, const float* __restrict__ lb,
           const unsigned short* __restrict__ w1b, const unsigned short* __restrict__ w2b,
           const float* __restrict__ b1f,
           const float* __restrict__ b2_0, const float* __restrict__ b2_1,
           const float* __restrict__ b2_2,
           const float* __restrict__ gamma, const float* __restrict__ l2) {
  __shared__ float T[64 * 129];                  // io tile [c][128 px + pad]
  __shared__ short Hs[8][64 * 20];               // per-wave gelu(H) [64 j][16 px + pad]

  int b  = blockIdx.x >> 9;
  int n0 = (blockIdx.x & 511) << 7;              // pixel base within batch
  int t  = threadIdx.x;
  int w  = t >> 6, l = t & 63;
  int l15 = l & 15, g = l >> 4;

  // fill T coalesced: T[c][p] = io[b][c][n0+p]
  size_t iob = ((size_t)b << 22) + n0;
  for (int i = 0; i < 16; ++i) {
    int idx = i * 512 + t;                       // 8192 = 64*128
    int c = idx >> 7, p = idx & 127;
    T[c * 129 + p] = io[iob + ((size_t)c << 16) + p];
  }
  __syncthreads();

  float l2v0 = l2[b * 3], l2v1 = l2[b * 3 + 1], l2v2 = l2[b * 3 + 2];

  // X A-frags: lane pixel p = 16w + l15, channels 8g+i (+32ks), LN applied
  int pl = (w << 4) + l15;                       // local pixel 0..127
  float muv = mu2[(b << 16) + n0 + pl];
  float rsv = rs2[(b << 16) + n0 + pl];
  short8 xf[2];
  #pragma unroll
  for (int ks = 0; ks < 2; ++ks)
    #pragma unroll
    for (int i = 0; i < 8; ++i) {
      int c = (ks << 5) + (g << 3) + i;
      float v = (T[c * 129 + pl] - muv) * rsv * lw[c] + lb[c];
      xf[ks][i] = (short)f2bs(v);
    }

  f32x4 acc2[4] = {{0,0,0,0},{0,0,0,0},{0,0,0,0},{0,0,0,0}};
  short* HsW = Hs[w];

  #pragma unroll 1
  for (int ch = 0; ch < 7; ++ch) {
    int jbase = ch << 6;
    float le = (ch == 0) ? l2v0 : (ch < 3 ? l2v1 : l2v2);
    // GEMM1: H[p][j] for 64 j, then gelu -> Hs
    #pragma unroll
    for (int nt = 0; nt < 4; ++nt) {
      int j0 = jbase + (nt << 4);
      int jl = j0 + l15;                         // absolute jt for this lane-col
      short8 bf0 = *(const short8*)(w1b + (jl << 6) + (g << 3));
      short8 bf1 = *(const short8*)(w1b + (jl << 6) + 32 + (g << 3));
      f32x4 a1 = {0.f, 0.f, 0.f, 0.f};
      a1 = __builtin_amdgcn_mfma_f32_16x16x32_bf16(xf[0], bf0, a1, 0, 0, 0);
      a1 = __builtin_amdgcn_mfma_f32_16x16x32_bf16(xf[1], bf1, a1, 0, 0, 0);
      float b1v = b1f[jl];
      short4 hp;
      #pragma unroll
      for (int r = 0; r < 4; ++r) {
        float tv = a1[r] + b1v;
        float gv = le * 0.5f * tv * (1.f + erff(tv * 0.70710678f));
        ((short*)&hp)[r] = (short)f2bs(gv);
      }
      // C/D: lane owns col j = j0+l15, rows p = 4g+r (packed 4 -> b64)
      *(short4*)(HsW + ((nt << 4) + l15) * 20 + (g << 2)) = hp;
    }
    // same-wave producer/consumer: wait LDS writes
    __builtin_amdgcn_s_waitcnt(0);               // lgkmcnt(0)
    // GEMM2: acc2[p][o] += G[p][j] * W2[j][o]
    #pragma unroll
    for (int kt = 0; kt < 2; ++kt) {
      short8 af;
      #pragma unroll
      for (int i = 0; i < 8; ++i)
        af[i] = HsW[((kt << 5) + (g << 3) + i) * 20 + l15];
      #pragma unroll
      for (int ot = 0; ot < 4; ++ot) {
        short8 bf = *(const short8*)(w2b + (((ot << 4) + l15) * 448) + jbase + (kt << 5) + (g << 3));
        acc2[ot] = __builtin_amdgcn_mfma_f32_16x16x32_bf16(af, bf, acc2[ot], 0, 0, 0);
      }
    }
  }

  // epilogue: add gamma*o1 + sum l2_e*b2_e, store into T (own pixel strip)
  #pragma unroll
  for (int ot = 0; ot < 4; ++ot) {
    int o = (ot << 4) + l15;
    float bias = l2v0 * b2_0[o] + l2v1 * b2_1[o] + l2v2 * b2_2[o];
    float gmv = gamma[o];
    #pragma unroll
    for (int r = 0; r < 4; ++r) {
      int p = (w << 4) + (g << 2) + r;
      float* tp = &T[o * 129 + p];
      *tp = acc2[ot][r] + gmv * (*tp) + bias;
    }
  }
  __syncthreads();

  // coalesced write-out
  for (int i = 0; i < 16; ++i) {
    int idx = i * 512 + t;
    int c = idx >> 7, p = idx & 127;
    io[iob + ((size_t)c << 16) + p] = T[c * 129 + p];
  }
}

extern "C" void kernel_launch(void* const* d_in, const int* in_sizes, int n_in,
                              void* d_out, int out_size, void* d_ws, size_t ws_size,
                              hipStream_t stream) {
  (void)in_sizes; (void)n_in; (void)out_size; (void)ws_size;
  const float* x        = (const float*)d_in[0];
  const float* hidden   = (const float*)d_in[1];
  const float* ln1_w    = (const float*)d_in[2];
  const float* ln1_b    = (const float*)d_in[3];
  const float* ln2_w    = (const float*)d_in[4];
  const float* ln2_b    = (const float*)d_in[5];
  const float* beta     = (const float*)d_in[6];
  const float* gamma    = (const float*)d_in[7];
  const float* att_temp = (const float*)d_in[8];
  const float* att_qkv  = (const float*)d_in[9];
  const float* att_dw   = (const float*)d_in[10];
  const float* att_proj = (const float*)d_in[11];
  const float* ar1_w    = (const float*)d_in[12];
  const float* ar1_b    = (const float*)d_in[13];
  const float* ar3_w    = (const float*)d_in[14];
  const float* ar3_b    = (const float*)d_in[15];
  const float* mr1_w    = (const float*)d_in[16];
  const float* mr1_b    = (const float*)d_in[17];
  const float* mr3_w    = (const float*)d_in[18];
  const float* mr3_b    = (const float*)d_in[19];
  const float* w1s[3] = {(const float*)d_in[20], (const float*)d_in[24], (const float*)d_in[28]};
  const float* b1s[3] = {(const float*)d_in[21], (const float*)d_in[25], (const float*)d_in[29]};
  const float* w2s[3] = {(const float*)d_in[22], (const float*)d_in[26], (const float*)d_in[30]};
  const float* b2s[3] = {(const float*)d_in[23], (const float*)d_in[27], (const float*)d_in[31]};

  // ---- workspace (~5.2 MB) ----
  float* F    = (float*)d_ws;
  float* mu1  = F + 0;          // 262144
  float* rs1  = F + 262144;     // 262144
  float* mu2  = F + 524288;     // 262144
  float* rs2  = F + 786432;     // 262144
  float* xg1  = F + 1048576;    // 256
  float* xg2  = F + 1048832;    // 256
  float* M    = F + 1049088;    // 16384
  float* h1a  = F + 1065472;    // 64
  float* h1m  = F + 1065536;    // 64
  float* l1   = F + 1065600;    // 16
  float* l2   = F + 1065616;    // 16
  float* Weff = F + 1065632;    // 49152
  float* Kt   = F + 1114784;    // 147456
  float* b1f  = F + 1262240;    // 448
  unsigned short* w1b = (unsigned short*)(F + 1262688);  // 28672 shorts
  unsigned short* w2b = (unsigned short*)(F + 1277024);  // 28672 shorts

  float* out_main   = (float*)d_out;             // also holds out1 between banks
  float* out_hidden = out_main + 16777216;
  float* out_logits = out_main + 16777280;

  // ---- attention bank ----
  k_stats<<<1024, 256, 0, stream>>>(x, mu1, rs1);
  k_xg   <<<256, 256, 0, stream>>>(x, mu1, rs1, ln1_w, ln1_b, xg1);
  k_zero <<<64, 256, 0, stream>>>(M, 16384);
  k_M    <<<256, 256, 0, stream>>>(x, mu1, rs1, ln1_w, ln1_b, M);
  k_route<<<1, 64, 0, stream>>>(xg1, hidden, ar1_w, ar1_b, ar3_w, ar3_b,
                                h1a, l1, out_logits, 0, nullptr);
  k_expw <<<12, 256, 0, stream>>>(M, att_qkv, att_temp, Weff);
  k_kmat <<<36, 256, 0, stream>>>(Weff, att_dw, att_proj, l1, Kt);
  k_conv <<<dim3(16, 16, 4), 256, 0, stream>>>(x, mu1, rs1, ln1_w, ln1_b, Kt,
                                               beta, out_main);
  // ---- MLP bank (out1 lives in d_out) ----
  k_stats<<<1024, 256, 0, stream>>>(out_main, mu2, rs2);
  k_xg   <<<256, 256, 0, stream>>>(out_main, mu2, rs2, ln2_w, ln2_b, xg2);
  k_route<<<1, 64, 0, stream>>>(xg2, h1a, mr1_w, mr1_b, mr3_w, mr3_b,
                                h1m, l2, out_logits, 1, out_hidden);
  k_prep <<<112, 256, 0, stream>>>(w1s[0], w1s[1], w1s[2], b1s[0], b1s[1], b1s[2],
                                   w2s[0], w2s[1], w2s[2], w1b, w2b, b1f);
  k_mlp  <<<2048, 512, 0, stream>>>(out_main, mu2, rs2, ln2_w, ln2_b,
                                    w1b, w2b, b1f, b2s[0], b2s[1], b2s[2],
                                    gamma, l2);
}

// Round 5
// 660.394 us; speedup vs baseline: 2.8234x; 1.4212x over previous
//
#include <hip/hip_runtime.h>
#include <hip/hip_bf16.h>
#include <cstddef>

using bf16 = __hip_bfloat16;
typedef __attribute__((ext_vector_type(8))) short short8;
typedef __attribute__((ext_vector_type(4))) float f32x4;

#define NPIX 65536  // 256*256

static __device__ __forceinline__ float b2f(bf16 v) { return __bfloat162float(v); }
static __device__ __forceinline__ bf16  f2b(float v) { return __float2bfloat16(v); }
static __device__ __forceinline__ unsigned short f2bs(float f) {
  union { float f; unsigned u; } v; v.f = f;
  unsigned r = (v.u + 0x7FFFu + ((v.u >> 16) & 1u)) >> 16;
  return (unsigned short)r;
}
static __device__ __forceinline__ float s2f(short s) {
  union { unsigned u; float f; } v; v.u = ((unsigned)(unsigned short)s) << 16;
  return v.f;
}

// ---------------- per-pixel LN stats: mu, rstd over 64 channels ----------------
__global__ void k_stats(const float* __restrict__ in, float* __restrict__ mu,
                        float* __restrict__ rs) {
  int pi = blockIdx.x * 256 + threadIdx.x;      // 0 .. B*N-1
  int b = pi >> 16, n = pi & 65535;
  const float* p = in + ((size_t)b << 22) + n;
  float s = 0.f, s2 = 0.f;
  #pragma unroll
  for (int c = 0; c < 64; ++c) {
    float v = p[(size_t)c << 16];
    s += v; s2 += v * v;
  }
  float m = s * 0.015625f;
  float var = s2 * 0.015625f - m * m;
  mu[pi] = m;
  rs[pi] = rsqrtf(var + 1e-5f);
}

// ---------------- xg[b][c] = mean over pixels of LN output ----------------
__global__ void k_xg(const float* __restrict__ in, const float* __restrict__ mu,
                     const float* __restrict__ rs, const float* __restrict__ w,
                     const float* __restrict__ bias, float* __restrict__ xg) {
  int bc = blockIdx.x;                           // 0..255  (b*64+c)
  int b = bc >> 6, c = bc & 63;
  const float* p = in + ((size_t)bc << 16);
  const float* mup = mu + (b << 16);
  const float* rsp = rs + (b << 16);
  float s = 0.f;
  for (int i = threadIdx.x; i < NPIX; i += 256)
    s += (p[i] - mup[i]) * rsp[i];
  #pragma unroll
  for (int o = 32; o > 0; o >>= 1) s += __shfl_down(s, o, 64);
  __shared__ float red[4];
  if ((threadIdx.x & 63) == 0) red[threadIdx.x >> 6] = s;
  __syncthreads();
  if (threadIdx.x == 0)
    xg[bc] = (red[0] + red[1] + red[2] + red[3]) * (1.f / 65536.f) * w[c] + bias[c];
}

__global__ void k_zero(float* __restrict__ p, int n) {
  int i = blockIdx.x * 256 + threadIdx.x;
  if (i < n) p[i] = 0.f;
}

// ---------------- Gram matrix M[b] = ln1 @ ln1^T  (64x64 per batch), LN inline ----------------
__global__ void k_M(const float* __restrict__ x, const float* __restrict__ mu,
                    const float* __restrict__ rs, const float* __restrict__ w,
                    const float* __restrict__ bias, float* __restrict__ M) {
  int b = blockIdx.x >> 6;
  int n0 = (blockIdx.x & 63) << 10;              // 1024 pixels per block
  __shared__ float tile[64][68];
  int ti = threadIdx.x >> 4, tj = threadIdx.x & 15;
  float acc[4][4] = {};
  for (int t0 = 0; t0 < 1024; t0 += 64) {
    __syncthreads();
    for (int idx = threadIdx.x; idx < 4096; idx += 256) {
      int ch = idx >> 6, px = idx & 63;
      int n = n0 + t0 + px;
      float xv = x[((size_t)(b * 64 + ch) << 16) + n];
      tile[ch][px] = (xv - mu[(b << 16) + n]) * rs[(b << 16) + n] * w[ch] + bias[ch];
    }
    __syncthreads();
    #pragma unroll 4
    for (int p = 0; p < 64; p += 4) {
      float4 av[4], bv[4];
      #pragma unroll
      for (int i = 0; i < 4; ++i) av[i] = *(const float4*)&tile[4 * ti + i][p];
      #pragma unroll
      for (int j = 0; j < 4; ++j) bv[j] = *(const float4*)&tile[4 * tj + j][p];
      #pragma unroll
      for (int i = 0; i < 4; ++i)
        #pragma unroll
        for (int j = 0; j < 4; ++j)
          acc[i][j] += av[i].x * bv[j].x + av[i].y * bv[j].y +
                       av[i].z * bv[j].z + av[i].w * bv[j].w;
    }
  }
  #pragma unroll
  for (int i = 0; i < 4; ++i)
    #pragma unroll
    for (int j = 0; j < 4; ++j)
      atomicAdd(&M[b * 4096 + (4 * ti + i) * 64 + (4 * tj + j)], acc[i][j]);
}

// ---------------- routing ----------------
__global__ void k_route(const float* __restrict__ xg, const float* __restrict__ hid,
                        const float* __restrict__ w1, const float* __restrict__ b1,
                        const float* __restrict__ w3, const float* __restrict__ b3,
                        float* __restrict__ h1_out, float* __restrict__ logit_out,
                        float* __restrict__ out_logits, int slot,
                        float* __restrict__ out_hidden) {
  __shared__ float h1s[4][16];
  int t = threadIdx.x;
  if (t < 64) {
    int b = t >> 4, j = t & 15;
    float a = b1[j];
    for (int c = 0; c < 64; ++c) a += w1[j * 80 + c] * xg[b * 64 + c];
    for (int k = 0; k < 16; ++k) a += w1[j * 80 + 64 + k] * hid[b * 16 + k];
    float g = 0.5f * a * (1.f + erff(a * 0.70710678f));   // exact gelu
    h1s[b][j] = g;
    h1_out[b * 16 + j] = g;
    if (out_hidden) out_hidden[b * 16 + j] = g;
  }
  __syncthreads();
  if (t < 12) {
    int b = t / 3, e = t % 3;
    float a = b3[e];
    for (int j = 0; j < 16; ++j) a += w3[e * 16 + j] * h1s[b][j];
    a = fmaxf(a, 0.f);
    logit_out[b * 3 + e] = a;
    out_logits[b * 6 + e * 2 + slot] = a;
  }
}

// ---------------- per (b,expert): softmax(q̂·k̂·temp) -> Weff = P @ Wv ----------------
__global__ void k_expw(const float* __restrict__ M, const float* __restrict__ qkv,
                       const float* __restrict__ temp, float* __restrict__ Weff) {
  int b = blockIdx.x / 3, e = blockIdx.x % 3;
  __shared__ float Ms[64][64];
  __shared__ float TQ[64][64];
  __shared__ float TK[64][64];
  __shared__ float P[64][4];
  __shared__ float nq[64], nk[64];
  const float* W = qkv + e * 12288;              // (192,64) for this expert
  for (int idx = threadIdx.x; idx < 4096; idx += 256)
    Ms[idx >> 6][idx & 63] = M[b * 4096 + idx];
  __syncthreads();
  {
    int r = threadIdx.x >> 2;
    int v0 = (threadIdx.x & 3) << 4;
    float aq[16] = {}, ak[16] = {};
    for (int u = 0; u < 64; ++u) {
      float wq = W[r * 64 + u];
      float wk = W[(64 + r) * 64 + u];
      #pragma unroll
      for (int i = 0; i < 16; ++i) {
        float m = Ms[u][v0 + i];
        aq[i] += wq * m; ak[i] += wk * m;
      }
    }
    #pragma unroll
    for (int i = 0; i < 16; ++i) { TQ[r][v0 + i] = aq[i]; TK[r][v0 + i] = ak[i]; }
  }
  __syncthreads();
  if (threadIdx.x < 64) {
    int c = threadIdx.x;
    float sq = 0.f, sk = 0.f;
    for (int v = 0; v < 64; ++v) {
      sq += TQ[c][v] * W[c * 64 + v];
      sk += TK[c][v] * W[(64 + c) * 64 + v];
    }
    nq[c] = fmaxf(sqrtf(fmaxf(sq, 0.f)), 1e-12f);
    nk[c] = fmaxf(sqrtf(fmaxf(sk, 0.f)), 1e-12f);
  }
  __syncthreads();
  if (threadIdx.x < 64) {
    int rr = threadIdx.x, h = rr >> 2;
    float tp = temp[e * 16 + h];
    float s[4];
    #pragma unroll
    for (int d = 0; d < 4; ++d) {
      int kc = h * 4 + d;
      float g = 0.f;
      for (int v = 0; v < 64; ++v) g += TQ[rr][v] * W[(64 + kc) * 64 + v];
      s[d] = g / (nq[rr] * nk[kc]) * tp;
    }
    float mx = fmaxf(fmaxf(s[0], s[1]), fmaxf(s[2], s[3]));
    float es[4], sum = 0.f;
    #pragma unroll
    for (int d = 0; d < 4; ++d) { es[d] = __expf(s[d] - mx); sum += es[d]; }
    float inv = 1.f / sum;
    #pragma unroll
    for (int d = 0; d < 4; ++d) P[rr][d] = es[d] * inv;
  }
  __syncthreads();
  if (threadIdx.x < 64) {
    int rr = threadIdx.x, h = rr >> 2;
    for (int u = 0; u < 64; ++u) {
      float a = 0.f;
      #pragma unroll
      for (int d = 0; d < 4; ++d)
        a += P[rr][d] * W[(128 + h * 4 + d) * 64 + u];
      Weff[(size_t)(b * 3 + e) * 4096 + rr * 64 + u] = a;
    }
  }
}

// ------ Ktb[b][tap][o][u] = bf16( Σ_e l1_e Proj_e[o,c] dw_e[c,tap] Weff_e[c,u] ) ------
__global__ void k_kmat(const float* __restrict__ Weff, const float* __restrict__ dw,
                       const float* __restrict__ proj, const float* __restrict__ l1,
                       unsigned short* __restrict__ Ktb) {
  int b = blockIdx.x / 9, t = blockIdx.x % 9;    // t = ky*3+kx
  __shared__ float S[64][68];
  __shared__ float Pr[64][68];
  int u = threadIdx.x >> 2, o0 = (threadIdx.x & 3) << 4;
  float acc[16] = {};
  for (int e = 0; e < 3; ++e) {
    __syncthreads();
    float le = l1[b * 3 + e];
    for (int idx = threadIdx.x; idx < 4096; idx += 256) {
      int c = idx >> 6, uu = idx & 63;
      S[c][uu] = le * dw[(e * 64 + c) * 9 + t] *
                 Weff[(size_t)(b * 3 + e) * 4096 + c * 64 + uu];
      Pr[c][uu] = proj[e * 4096 + uu * 64 + c];
    }
    __syncthreads();
    for (int c = 0; c < 64; ++c) {
      float sv = S[c][u];
      #pragma unroll
      for (int i = 0; i < 16; ++i) acc[i] += Pr[c][o0 + i] * sv;
    }
  }
  #pragma unroll
  for (int i = 0; i < 16; ++i)                   // Ktb[tap][o][u]
    Ktb[(size_t)(b * 9 + t) * 4096 + (o0 + i) * 64 + u] = f2bs(acc[i]);
}

// -------- MFMA collapsed attention bank: out1 = Conv3x3(ln1(x); Ktb[b]) + beta*x --------
// block 256 thr (4 waves) = 16x16 px tile; halo [324 px][64 c] bf16, XOR-swizzled
__global__ __launch_bounds__(256, 3)
void k_conv(const float* __restrict__ x, const float* __restrict__ mu,
            const float* __restrict__ rs, const float* __restrict__ lw,
            const float* __restrict__ lb, const unsigned short* __restrict__ Ktb,
            const float* __restrict__ beta, float* __restrict__ out1) {
  __shared__ __align__(16) short lds[20736];     // 41472 B; reused for result

  int x0 = blockIdx.x << 4, y0 = blockIdx.y << 4, b = blockIdx.z;

  // halo fill: lds[hpix][c], 16B-block of c XOR'd with (hpix&7)
  for (int idx = threadIdx.x; idx < 20736; idx += 256) {
    int c = idx / 324, hpix = idx - c * 324;
    int hy = hpix / 18, hx = hpix - hy * 18;
    int gy = y0 + hy - 1, gx = x0 + hx - 1;
    float v = 0.f;
    if ((unsigned)gy < 256u && (unsigned)gx < 256u) {
      int n = (gy << 8) + gx;
      float xv = x[((size_t)(b * 64 + c) << 16) + n];
      v = (xv - mu[(b << 16) + n]) * rs[(b << 16) + n] * lw[c] + lb[c];
    }
    lds[hpix * 64 + ((((c >> 3) ^ (hpix & 7)) << 3) | (c & 7))] = (short)f2bs(v);
  }
  __syncthreads();

  int w = threadIdx.x >> 6, l = threadIdx.x & 63;
  int l15 = l & 15, g = l >> 4;

  f32x4 acc[4][4] = {};                          // [mi][ot]; wave rows tm = 4w+mi
  const unsigned short* Kb = Ktb + (size_t)b * 9 * 4096;

  #pragma unroll 1
  for (int tap = 0; tap < 9; ++tap) {
    int ky = tap / 3, kx = tap - ky * 3;
    const unsigned short* Kt = Kb + (tap << 12);
    #pragma unroll
    for (int ks = 0; ks < 2; ++ks) {
      short8 bfr[4];
      #pragma unroll
      for (int ot = 0; ot < 4; ++ot)             // B[k=u][col=o] from Ktb[o][u]
        bfr[ot] = *(const short8*)(Kt + (((ot << 4) + l15) << 6) + (ks << 5) + (g << 3));
      int blk = ((ks << 2) | g);                 // c0>>3
      #pragma unroll
      for (int mi = 0; mi < 4; ++mi) {
        int hpix = ((w << 2) + mi + ky) * 18 + l15 + kx;
        short8 af = *(const short8*)(lds + hpix * 64 + ((blk ^ (hpix & 7)) << 3));
        #pragma unroll
        for (int ot = 0; ot < 4; ++ot)
          acc[mi][ot] = __builtin_amdgcn_mfma_f32_16x16x32_bf16(af, bfr[ot], acc[mi][ot], 0, 0, 0);
      }
    }
  }

  __syncthreads();                               // halo reads done; reuse lds as Rs[o][260]
  #pragma unroll
  for (int mi = 0; mi < 4; ++mi) {
    int p0 = (((w << 2) + mi) << 4) + (g << 2);
    #pragma unroll
    for (int ot = 0; ot < 4; ++ot) {
      int o = (ot << 4) + l15;
      short4 pk;
      pk.x = (short)f2bs(acc[mi][ot][0]);
      pk.y = (short)f2bs(acc[mi][ot][1]);
      pk.z = (short)f2bs(acc[mi][ot][2]);
      pk.w = (short)f2bs(acc[mi][ot][3]);
      *(short4*)(lds + o * 260 + p0) = pk;
    }
  }
  __syncthreads();

  // coalesced residual + store
  for (int idx = threadIdx.x; idx < 16384; idx += 256) {
    int c = idx >> 8, p = idx & 255;
    int n = ((y0 + (p >> 4)) << 8) + x0 + (p & 15);
    size_t gi = ((size_t)(b * 64 + c) << 16) + n;
    out1[gi] = s2f(lds[c * 260 + p]) + beta[c] * x[gi];
  }
}

// ---------------- prep MLP weights as bf16: w1b[jt][c], w2b[o][jt], b1f[jt] ----------------
__global__ void k_prep(const float* __restrict__ w1_0, const float* __restrict__ w1_1,
                       const float* __restrict__ w1_2,
                       const float* __restrict__ b1_0, const float* __restrict__ b1_1,
                       const float* __restrict__ b1_2,
                       const float* __restrict__ w2_0, const float* __restrict__ w2_1,
                       const float* __restrict__ w2_2,
                       unsigned short* __restrict__ w1b, unsigned short* __restrict__ w2b,
                       float* __restrict__ b1f) {
  int idx = blockIdx.x * 256 + threadIdx.x;      // 112*256 = 28672 = 448*64
  if (idx >= 448 * 64) return;
  int jt = idx >> 6, c = idx & 63;
  int e, j;
  if (jt < 64)       { e = 0; j = jt; }
  else if (jt < 192) { e = 1; j = jt - 64; }
  else               { e = 2; j = jt - 192; }
  const float* w1 = e == 0 ? w1_0 : (e == 1 ? w1_1 : w1_2);
  const float* w2 = e == 0 ? w2_0 : (e == 1 ? w2_1 : w2_2);
  int hf = 64 << e;
  w1b[jt * 64 + c]  = f2bs(w1[j * 64 + c]);
  w2b[c * 448 + jt] = f2bs(w2[c * hf + j]);
  if (c == 0) {
    const float* b1 = e == 0 ? b1_0 : (e == 1 ? b1_1 : b1_2);
    b1f[jt] = b1[j];
  }
}

// ---------------- MFMA fused MLP bank: io = Σ_e l2_e MLP_e(ln2(io)) + gamma*io ----------------
__global__ __launch_bounds__(512, 2)
void k_mlp(float* io,
           const float* __restrict__ mu2, const float* __restrict__ rs2,
           const float* __restrict__ lw, const float* __restrict__ lb,
           const unsigned short* __restrict__ w1b, const unsigned short* __restrict__ w2b,
           const float* __restrict__ b1f,
           const float* __restrict__ b2_0, const float* __restrict__ b2_1,
           const float* __restrict__ b2_2,
           const float* __restrict__ gamma, const float* __restrict__ l2) {
  __shared__ float T[64 * 129];                  // io tile [c][128 px + pad]
  __shared__ short Hs[8][64 * 20];               // per-wave gelu(H) [64 j][16 px + pad]

  int b  = blockIdx.x >> 9;
  int n0 = (blockIdx.x & 511) << 7;              // pixel base within batch
  int t  = threadIdx.x;
  int w  = t >> 6, l = t & 63;
  int l15 = l & 15, g = l >> 4;

  size_t iob = ((size_t)b << 22) + n0;
  for (int i = 0; i < 16; ++i) {
    int idx = i * 512 + t;
    int c = idx >> 7, p = idx & 127;
    T[c * 129 + p] = io[iob + ((size_t)c << 16) + p];
  }
  __syncthreads();

  float l2v0 = l2[b * 3], l2v1 = l2[b * 3 + 1], l2v2 = l2[b * 3 + 2];

  int pl = (w << 4) + l15;
  float muv = mu2[(b << 16) + n0 + pl];
  float rsv = rs2[(b << 16) + n0 + pl];
  short8 xf[2];
  #pragma unroll
  for (int ks = 0; ks < 2; ++ks)
    #pragma unroll
    for (int i = 0; i < 8; ++i) {
      int c = (ks << 5) + (g << 3) + i;
      float v = (T[c * 129 + pl] - muv) * rsv * lw[c] + lb[c];
      xf[ks][i] = (short)f2bs(v);
    }

  f32x4 acc2[4] = {{0,0,0,0},{0,0,0,0},{0,0,0,0},{0,0,0,0}};
  short* HsW = Hs[w];

  #pragma unroll 1
  for (int ch = 0; ch < 7; ++ch) {
    int jbase = ch << 6;
    float le = (ch == 0) ? l2v0 : (ch < 3 ? l2v1 : l2v2);
    #pragma unroll
    for (int nt = 0; nt < 4; ++nt) {
      int jl = jbase + (nt << 4) + l15;
      short8 bf0 = *(const short8*)(w1b + (jl << 6) + (g << 3));
      short8 bf1 = *(const short8*)(w1b + (jl << 6) + 32 + (g << 3));
      f32x4 a1 = {0.f, 0.f, 0.f, 0.f};
      a1 = __builtin_amdgcn_mfma_f32_16x16x32_bf16(xf[0], bf0, a1, 0, 0, 0);
      a1 = __builtin_amdgcn_mfma_f32_16x16x32_bf16(xf[1], bf1, a1, 0, 0, 0);
      float b1v = b1f[jl];
      short4 hp;
      #pragma unroll
      for (int r = 0; r < 4; ++r) {
        float tv = a1[r] + b1v;
        float gv = le * 0.5f * tv * (1.f + erff(tv * 0.70710678f));
        ((short*)&hp)[r] = (short)f2bs(gv);
      }
      *(short4*)(HsW + ((nt << 4) + l15) * 20 + (g << 2)) = hp;
    }
    __builtin_amdgcn_s_waitcnt(0);
    #pragma unroll
    for (int kt = 0; kt < 2; ++kt) {
      short8 af;
      #pragma unroll
      for (int i = 0; i < 8; ++i)
        af[i] = HsW[((kt << 5) + (g << 3) + i) * 20 + l15];
      #pragma unroll
      for (int ot = 0; ot < 4; ++ot) {
        short8 bf = *(const short8*)(w2b + (((ot << 4) + l15) * 448) + jbase + (kt << 5) + (g << 3));
        acc2[ot] = __builtin_amdgcn_mfma_f32_16x16x32_bf16(af, bf, acc2[ot], 0, 0, 0);
      }
    }
  }

  #pragma unroll
  for (int ot = 0; ot < 4; ++ot) {
    int o = (ot << 4) + l15;
    float bias = l2v0 * b2_0[o] + l2v1 * b2_1[o] + l2v2 * b2_2[o];
    float gmv = gamma[o];
    #pragma unroll
    for (int r = 0; r < 4; ++r) {
      int p = (w << 4) + (g << 2) + r;
      float* tp = &T[o * 129 + p];
      *tp = acc2[ot][r] + gmv * (*tp) + bias;
    }
  }
  __syncthreads();

  for (int i = 0; i < 16; ++i) {
    int idx = i * 512 + t;
    int c = idx >> 7, p = idx & 127;
    io[iob + ((size_t)c << 16) + p] = T[c * 129 + p];
  }
}

extern "C" void kernel_launch(void* const* d_in, const int* in_sizes, int n_in,
                              void* d_out, int out_size, void* d_ws, size_t ws_size,
                              hipStream_t stream) {
  (void)in_sizes; (void)n_in; (void)out_size; (void)ws_size;
  const float* x        = (const float*)d_in[0];
  const float* hidden   = (const float*)d_in[1];
  const float* ln1_w    = (const float*)d_in[2];
  const float* ln1_b    = (const float*)d_in[3];
  const float* ln2_w    = (const float*)d_in[4];
  const float* ln2_b    = (const float*)d_in[5];
  const float* beta     = (const float*)d_in[6];
  const float* gamma    = (const float*)d_in[7];
  const float* att_temp = (const float*)d_in[8];
  const float* att_qkv  = (const float*)d_in[9];
  const float* att_dw   = (const float*)d_in[10];
  const float* att_proj = (const float*)d_in[11];
  const float* ar1_w    = (const float*)d_in[12];
  const float* ar1_b    = (const float*)d_in[13];
  const float* ar3_w    = (const float*)d_in[14];
  const float* ar3_b    = (const float*)d_in[15];
  const float* mr1_w    = (const float*)d_in[16];
  const float* mr1_b    = (const float*)d_in[17];
  const float* mr3_w    = (const float*)d_in[18];
  const float* mr3_b    = (const float*)d_in[19];
  const float* w1s[3] = {(const float*)d_in[20], (const float*)d_in[24], (const float*)d_in[28]};
  const float* b1s[3] = {(const float*)d_in[21], (const float*)d_in[25], (const float*)d_in[29]};
  const float* w2s[3] = {(const float*)d_in[22], (const float*)d_in[26], (const float*)d_in[30]};
  const float* b2s[3] = {(const float*)d_in[23], (const float*)d_in[27], (const float*)d_in[31]};

  // ---- workspace (~4.9 MB) ----
  float* F    = (float*)d_ws;
  float* mu1  = F + 0;          // 262144
  float* rs1  = F + 262144;     // 262144
  float* mu2  = F + 524288;     // 262144
  float* rs2  = F + 786432;     // 262144
  float* xg1  = F + 1048576;    // 256
  float* xg2  = F + 1048832;    // 256
  float* M    = F + 1049088;    // 16384
  float* h1a  = F + 1065472;    // 64
  float* h1m  = F + 1065536;    // 64
  float* l1   = F + 1065600;    // 16
  float* l2   = F + 1065616;    // 16
  float* Weff = F + 1065632;    // 49152
  unsigned short* Ktb = (unsigned short*)(F + 1114784);  // 147456 ushorts (73728 f)
  float* b1f  = F + 1188512;    // 448
  unsigned short* w1b = (unsigned short*)(F + 1188960);  // 28672 ushorts
  unsigned short* w2b = (unsigned short*)(F + 1203296);  // 28672 ushorts

  float* out_main   = (float*)d_out;             // also holds out1 between banks
  float* out_hidden = out_main + 16777216;
  float* out_logits = out_main + 16777280;

  // ---- attention bank ----
  k_stats<<<1024, 256, 0, stream>>>(x, mu1, rs1);
  k_xg   <<<256, 256, 0, stream>>>(x, mu1, rs1, ln1_w, ln1_b, xg1);
  k_zero <<<64, 256, 0, stream>>>(M, 16384);
  k_M    <<<256, 256, 0, stream>>>(x, mu1, rs1, ln1_w, ln1_b, M);
  k_route<<<1, 64, 0, stream>>>(xg1, hidden, ar1_w, ar1_b, ar3_w, ar3_b,
                                h1a, l1, out_logits, 0, nullptr);
  k_expw <<<12, 256, 0, stream>>>(M, att_qkv, att_temp, Weff);
  k_kmat <<<36, 256, 0, stream>>>(Weff, att_dw, att_proj, l1, Ktb);
  k_conv <<<dim3(16, 16, 4), 256, 0, stream>>>(x, mu1, rs1, ln1_w, ln1_b, Ktb,
                                               beta, out_main);
  // ---- MLP bank (out1 lives in d_out) ----
  k_stats<<<1024, 256, 0, stream>>>(out_main, mu2, rs2);
  k_xg   <<<256, 256, 0, stream>>>(out_main, mu2, rs2, ln2_w, ln2_b, xg2);
  k_route<<<1, 64, 0, stream>>>(xg2, h1a, mr1_w, mr1_b, mr3_w, mr3_b,
                                h1m, l2, out_logits, 1, out_hidden);
  k_prep <<<112, 256, 0, stream>>>(w1s[0], w1s[1], w1s[2], b1s[0], b1s[1], b1s[2],
                                   w2s[0], w2s[1], w2s[2], w1b, w2b, b1f);
  k_mlp  <<<2048, 512, 0, stream>>>(out_main, mu2, rs2, ln2_w, ln2_b,
                                    w1b, w2b, b1f, b2s[0], b2s[1], b2s[2],
                                    gamma, l2);
}

// Round 6
// 519.061 us; speedup vs baseline: 3.5922x; 1.2723x over previous
//
#include <hip/hip_runtime.h>
#include <hip/hip_bf16.h>
#include <cstddef>

typedef __attribute__((ext_vector_type(8))) short short8;
typedef __attribute__((ext_vector_type(4))) float f32x4;

#define NPIX 65536  // 256*256

static __device__ __forceinline__ unsigned short f2bs(float f) {
  union { float f; unsigned u; } v; v.f = f;
  unsigned r = (v.u + 0x7FFFu + ((v.u >> 16) & 1u)) >> 16;
  return (unsigned short)r;
}
static __device__ __forceinline__ float s2f(short s) {
  union { unsigned u; float f; } v; v.u = ((unsigned)(unsigned short)s) << 16;
  return v.f;
}

__global__ void k_zero(float* __restrict__ p, int n) {
  int i = blockIdx.x * 256 + threadIdx.x;
  if (i < n) p[i] = 0.f;
}

// ---- fused bank-1 pre-pass: mu1/rs1 per pixel, xg1 channel sums, Gram M (MFMA) ----
// 1024 blocks x 256 thr; block = 256 consecutive pixels of one batch
__global__ __launch_bounds__(256, 4)
void k_statsxg(const float* __restrict__ in, float* __restrict__ mu,
               float* __restrict__ rs, const float* __restrict__ lnw,
               const float* __restrict__ lnb, float* __restrict__ Ssum,
               float* __restrict__ M) {
  __shared__ __align__(16) short tile[64 * 264];   // [c][256 px + pad]
  __shared__ float wred[4][64];
  int t = threadIdx.x;
  int pi = blockIdx.x * 256 + t;
  int b = blockIdx.x >> 8;
  const float* p = in + ((size_t)b << 22) + (pi & 65535);
  float s = 0.f, s2 = 0.f;
  #pragma unroll
  for (int c = 0; c < 64; ++c) {
    float v = p[(size_t)c << 16];
    s += v; s2 += v * v;
    tile[c * 264 + t] = (short)f2bs(v);
  }
  float m = s * 0.015625f;
  float var = s2 * 0.015625f - m * m;
  float rstd = rsqrtf(var + 1e-5f);
  mu[pi] = m; rs[pi] = rstd;
  int l = t & 63, w = t >> 6, l15 = l & 15, g = l >> 4;
  for (int c = 0; c < 64; ++c) {
    float lnv = (s2f(tile[c * 264 + t]) - m) * rstd * lnw[c] + lnb[c];
    tile[c * 264 + t] = (short)f2bs(lnv);          // own column only
    float r = lnv;
    #pragma unroll
    for (int o = 32; o > 0; o >>= 1) r += __shfl_down(r, o, 64);
    if (l == 0) wred[w][c] = r;
  }
  __syncthreads();
  if (t < 64)
    atomicAdd(&Ssum[b * 64 + t],
              wred[0][t] + wred[1][t] + wred[2][t] + wred[3][t]);
  // Gram: wave w computes rows 16w..16w+15 x all 64 cols, K = 256 px
  f32x4 ga[4] = {{0,0,0,0},{0,0,0,0},{0,0,0,0},{0,0,0,0}};
  #pragma unroll
  for (int kt = 0; kt < 8; ++kt) {
    short8 af = *(const short8*)(tile + (16 * w + l15) * 264 + (kt << 5) + (g << 3));
    #pragma unroll
    for (int ot = 0; ot < 4; ++ot) {
      short8 bfg = *(const short8*)(tile + ((ot << 4) + l15) * 264 + (kt << 5) + (g << 3));
      ga[ot] = __builtin_amdgcn_mfma_f32_16x16x32_bf16(af, bfg, ga[ot], 0, 0, 0);
    }
  }
  float* Mb = M + b * 4096;
  #pragma unroll
  for (int ot = 0; ot < 4; ++ot)
    #pragma unroll
    for (int r = 0; r < 4; ++r)
      atomicAdd(&Mb[(16 * w + (g << 2) + r) * 64 + (ot << 4) + l15], ga[ot][r]);
}

// ---------------- routing: xg from channel-sums; h1 = gelu(...); logit = relu(...) ----------------
__global__ void k_route(const float* __restrict__ Ssum, const float* __restrict__ hid,
                        const float* __restrict__ w1, const float* __restrict__ b1,
                        const float* __restrict__ w3, const float* __restrict__ b3,
                        float* __restrict__ h1_out, float* __restrict__ logit_out,
                        float* __restrict__ out_logits, int slot,
                        float* __restrict__ out_hidden) {
  __shared__ float xgs[4][64];
  __shared__ float h1s[4][16];
  int t = threadIdx.x;                             // 64 threads
  for (int i = t; i < 256; i += 64)
    xgs[i >> 6][i & 63] = Ssum[i] * (1.f / 65536.f);
  __syncthreads();
  {
    int b = t >> 4, j = t & 15;
    float a = b1[j];
    for (int c = 0; c < 64; ++c) a += w1[j * 80 + c] * xgs[b][c];
    for (int k = 0; k < 16; ++k) a += w1[j * 80 + 64 + k] * hid[b * 16 + k];
    float g = 0.5f * a * (1.f + erff(a * 0.70710678f));   // exact gelu
    h1s[b][j] = g;
    h1_out[b * 16 + j] = g;
    if (out_hidden) out_hidden[b * 16 + j] = g;
  }
  __syncthreads();
  if (t < 12) {
    int b = t / 3, e = t % 3;
    float a = b3[e];
    for (int j = 0; j < 16; ++j) a += w3[e * 16 + j] * h1s[b][j];
    a = fmaxf(a, 0.f);
    logit_out[b * 3 + e] = a;
    out_logits[b * 6 + e * 2 + slot] = a;
  }
}

// ---------------- per (b,expert): softmax(q̂·k̂·temp) -> Weff = P @ Wv ----------------
__global__ void k_expw(const float* __restrict__ M, const float* __restrict__ qkv,
                       const float* __restrict__ temp, float* __restrict__ Weff) {
  int b = blockIdx.x / 3, e = blockIdx.x % 3;
  __shared__ float Ms[64][64];
  __shared__ float TQ[64][64];
  __shared__ float TK[64][64];
  __shared__ float P[64][4];
  __shared__ float nq[64], nk[64];
  const float* W = qkv + e * 12288;
  for (int idx = threadIdx.x; idx < 4096; idx += 256)
    Ms[idx >> 6][idx & 63] = M[b * 4096 + idx];
  __syncthreads();
  {
    int r = threadIdx.x >> 2;
    int v0 = (threadIdx.x & 3) << 4;
    float aq[16] = {}, ak[16] = {};
    for (int u = 0; u < 64; ++u) {
      float wq = W[r * 64 + u];
      float wk = W[(64 + r) * 64 + u];
      #pragma unroll
      for (int i = 0; i < 16; ++i) {
        float m = Ms[u][v0 + i];
        aq[i] += wq * m; ak[i] += wk * m;
      }
    }
    #pragma unroll
    for (int i = 0; i < 16; ++i) { TQ[r][v0 + i] = aq[i]; TK[r][v0 + i] = ak[i]; }
  }
  __syncthreads();
  if (threadIdx.x < 64) {
    int c = threadIdx.x;
    float sq = 0.f, sk = 0.f;
    for (int v = 0; v < 64; ++v) {
      sq += TQ[c][v] * W[c * 64 + v];
      sk += TK[c][v] * W[(64 + c) * 64 + v];
    }
    nq[c] = fmaxf(sqrtf(fmaxf(sq, 0.f)), 1e-12f);
    nk[c] = fmaxf(sqrtf(fmaxf(sk, 0.f)), 1e-12f);
  }
  __syncthreads();
  if (threadIdx.x < 64) {
    int rr = threadIdx.x, h = rr >> 2;
    float tp = temp[e * 16 + h];
    float s[4];
    #pragma unroll
    for (int d = 0; d < 4; ++d) {
      int kc = h * 4 + d;
      float g = 0.f;
      for (int v = 0; v < 64; ++v) g += TQ[rr][v] * W[(64 + kc) * 64 + v];
      s[d] = g / (nq[rr] * nk[kc]) * tp;
    }
    float mx = fmaxf(fmaxf(s[0], s[1]), fmaxf(s[2], s[3]));
    float es[4], sum = 0.f;
    #pragma unroll
    for (int d = 0; d < 4; ++d) { es[d] = __expf(s[d] - mx); sum += es[d]; }
    float inv = 1.f / sum;
    #pragma unroll
    for (int d = 0; d < 4; ++d) P[rr][d] = es[d] * inv;
  }
  __syncthreads();
  if (threadIdx.x < 64) {
    int rr = threadIdx.x, h = rr >> 2;
    for (int u = 0; u < 64; ++u) {
      float a = 0.f;
      #pragma unroll
      for (int d = 0; d < 4; ++d)
        a += P[rr][d] * W[(128 + h * 4 + d) * 64 + u];
      Weff[(size_t)(b * 3 + e) * 4096 + rr * 64 + u] = a;
    }
  }
}

// ------ Ktb[b][tap][o][u] = bf16( Σ_e l1_e Proj_e[o,c] dw_e[c,tap] Weff_e[c,u] ) ------
__global__ void k_kmat(const float* __restrict__ Weff, const float* __restrict__ dw,
                       const float* __restrict__ proj, const float* __restrict__ l1,
                       unsigned short* __restrict__ Ktb) {
  int b = blockIdx.x / 9, t = blockIdx.x % 9;
  __shared__ float S[64][68];
  __shared__ float Pr[64][68];
  int u = threadIdx.x >> 2, o0 = (threadIdx.x & 3) << 4;
  float acc[16] = {};
  for (int e = 0; e < 3; ++e) {
    __syncthreads();
    float le = l1[b * 3 + e];
    for (int idx = threadIdx.x; idx < 4096; idx += 256) {
      int c = idx >> 6, uu = idx & 63;
      S[c][uu] = le * dw[(e * 64 + c) * 9 + t] *
                 Weff[(size_t)(b * 3 + e) * 4096 + c * 64 + uu];
      Pr[c][uu] = proj[e * 4096 + uu * 64 + c];
    }
    __syncthreads();
    for (int c = 0; c < 64; ++c) {
      float sv = S[c][u];
      #pragma unroll
      for (int i = 0; i < 16; ++i) acc[i] += Pr[c][o0 + i] * sv;
    }
  }
  #pragma unroll
  for (int i = 0; i < 16; ++i)
    Ktb[(size_t)(b * 9 + t) * 4096 + (o0 + i) * 64 + u] = f2bs(acc[i]);
}

// -------- MFMA conv + residual + fused LN2 stats + xg2 sums --------
__global__ __launch_bounds__(256, 3)
void k_conv(const float* __restrict__ x, const float* __restrict__ mu,
            const float* __restrict__ rs, const float* __restrict__ lw,
            const float* __restrict__ lb, const unsigned short* __restrict__ Ktb,
            const float* __restrict__ beta, float* __restrict__ out1,
            const float* __restrict__ lw2, const float* __restrict__ lb2,
            float* __restrict__ mu2, float* __restrict__ rs2,
            float* __restrict__ Ssum2) {
  __shared__ __align__(16) short lds[20736];     // halo, then result [o][260]
  __shared__ float wred[4][64];

  int x0 = blockIdx.x << 4, y0 = blockIdx.y << 4, b = blockIdx.z;

  for (int idx = threadIdx.x; idx < 20736; idx += 256) {
    int c = idx / 324, hpix = idx - c * 324;
    int hy = hpix / 18, hx = hpix - hy * 18;
    int gy = y0 + hy - 1, gx = x0 + hx - 1;
    float v = 0.f;
    if ((unsigned)gy < 256u && (unsigned)gx < 256u) {
      int n = (gy << 8) + gx;
      float xv = x[((size_t)(b * 64 + c) << 16) + n];
      v = (xv - mu[(b << 16) + n]) * rs[(b << 16) + n] * lw[c] + lb[c];
    }
    lds[hpix * 64 + ((((c >> 3) ^ (hpix & 7)) << 3) | (c & 7))] = (short)f2bs(v);
  }
  __syncthreads();

  int w = threadIdx.x >> 6, l = threadIdx.x & 63;
  int l15 = l & 15, g = l >> 4;

  f32x4 acc[4][4] = {};
  const unsigned short* Kb = Ktb + (size_t)b * 9 * 4096;

  #pragma unroll 1
  for (int tap = 0; tap < 9; ++tap) {
    int ky = tap / 3, kx = tap - ky * 3;
    const unsigned short* Kt = Kb + (tap << 12);
    #pragma unroll
    for (int ks = 0; ks < 2; ++ks) {
      short8 bfr[4];
      #pragma unroll
      for (int ot = 0; ot < 4; ++ot)
        bfr[ot] = *(const short8*)(Kt + (((ot << 4) + l15) << 6) + (ks << 5) + (g << 3));
      int blk = ((ks << 2) | g);
      #pragma unroll
      for (int mi = 0; mi < 4; ++mi) {
        int hpix = ((w << 2) + mi + ky) * 18 + l15 + kx;
        short8 af = *(const short8*)(lds + hpix * 64 + ((blk ^ (hpix & 7)) << 3));
        #pragma unroll
        for (int ot = 0; ot < 4; ++ot)
          acc[mi][ot] = __builtin_amdgcn_mfma_f32_16x16x32_bf16(af, bfr[ot], acc[mi][ot], 0, 0, 0);
      }
    }
  }

  __syncthreads();                               // reuse lds as Rs[o][260]
  #pragma unroll
  for (int mi = 0; mi < 4; ++mi) {
    int p0 = (((w << 2) + mi) << 4) + (g << 2);
    #pragma unroll
    for (int ot = 0; ot < 4; ++ot) {
      int o = (ot << 4) + l15;
      short4 pk;
      pk.x = (short)f2bs(acc[mi][ot][0]);
      pk.y = (short)f2bs(acc[mi][ot][1]);
      pk.z = (short)f2bs(acc[mi][ot][2]);
      pk.w = (short)f2bs(acc[mi][ot][3]);
      *(short4*)(lds + o * 260 + p0) = pk;
    }
  }
  __syncthreads();

  // residual + store + LN2 stats (thread owns pixel p2)
  int p2 = threadIdx.x;
  int n = ((y0 + (p2 >> 4)) << 8) + x0 + (p2 & 15);
  float s = 0.f, s2 = 0.f;
  #pragma unroll
  for (int c = 0; c < 64; ++c) {
    size_t gi = ((size_t)(b * 64 + c) << 16) + n;
    float v = s2f(lds[c * 260 + p2]) + beta[c] * x[gi];
    out1[gi] = v;
    s += v; s2 += v * v;
    lds[c * 260 + p2] = (short)f2bs(v);          // own column only
  }
  float m = s * 0.015625f;
  float var = s2 * 0.015625f - m * m;
  float rstd = rsqrtf(var + 1e-5f);
  mu2[(b << 16) + n] = m;
  rs2[(b << 16) + n] = rstd;
  for (int c = 0; c < 64; ++c) {
    float lnv = (s2f(lds[c * 260 + p2]) - m) * rstd * lw2[c] + lb2[c];
    #pragma unroll
    for (int o = 32; o > 0; o >>= 1) lnv += __shfl_down(lnv, o, 64);
    if (l == 0) wred[w][c] = lnv;
  }
  __syncthreads();
  if (threadIdx.x < 64)
    atomicAdd(&Ssum2[b * 64 + threadIdx.x],
              wred[0][threadIdx.x] + wred[1][threadIdx.x] +
              wred[2][threadIdx.x] + wred[3][threadIdx.x]);
}

// ---------------- prep MLP weights as bf16: w1b[jt][c], w2b[o][jt], b1f[jt] ----------------
__global__ void k_prep(const float* __restrict__ w1_0, const float* __restrict__ w1_1,
                       const float* __restrict__ w1_2,
                       const float* __restrict__ b1_0, const float* __restrict__ b1_1,
                       const float* __restrict__ b1_2,
                       const float* __restrict__ w2_0, const float* __restrict__ w2_1,
                       const float* __restrict__ w2_2,
                       unsigned short* __restrict__ w1b, unsigned short* __restrict__ w2b,
                       float* __restrict__ b1f) {
  int idx = blockIdx.x * 256 + threadIdx.x;
  if (idx >= 448 * 64) return;
  int jt = idx >> 6, c = idx & 63;
  int e, j;
  if (jt < 64)       { e = 0; j = jt; }
  else if (jt < 192) { e = 1; j = jt - 64; }
  else               { e = 2; j = jt - 192; }
  const float* w1 = e == 0 ? w1_0 : (e == 1 ? w1_1 : w1_2);
  const float* w2 = e == 0 ? w2_0 : (e == 1 ? w2_1 : w2_2);
  int hf = 64 << e;
  w1b[jt * 64 + c]  = f2bs(w1[j * 64 + c]);
  w2b[c * 448 + jt] = f2bs(w2[c * hf + j]);
  if (c == 0) {
    const float* b1 = e == 0 ? b1_0 : (e == 1 ? b1_1 : b1_2);
    b1f[jt] = b1[j];
  }
}

// ---------------- MFMA fused MLP bank: io = Σ_e l2_e MLP_e(ln2(io)) + gamma*io ----------------
// GEMM1 swapped (D[j][p]) so H lands j-contiguous per pixel -> b128 A-frag reads
__global__ __launch_bounds__(512, 6)
void k_mlp(float* io,
           const float* __restrict__ mu2, const float* __restrict__ rs2,
           const float* __restrict__ lw, const float* __restrict__ lb,
           const unsigned short* __restrict__ w1b, const unsigned short* __restrict__ w2b,
           const float* __restrict__ b1f,
           const float* __restrict__ b2_0, const float* __restrict__ b2_1,
           const float* __restrict__ b2_2,
           const float* __restrict__ gamma, const float* __restrict__ l2) {
  __shared__ float T[64 * 129];                  // io tile [c][128 px + pad]
  __shared__ __align__(16) short Hs[8][16 * 80]; // per-wave [px][80 j-slots]

  int b  = blockIdx.x >> 9;
  int n0 = (blockIdx.x & 511) << 7;
  int t  = threadIdx.x;
  int w  = t >> 6, l = t & 63;
  int l15 = l & 15, g = l >> 4;

  size_t iob = ((size_t)b << 22) + n0;
  for (int i = 0; i < 16; ++i) {
    int idx = i * 512 + t;
    int c = idx >> 7, p = idx & 127;
    T[c * 129 + p] = io[iob + ((size_t)c << 16) + p];
  }
  __syncthreads();

  float l2v0 = l2[b * 3], l2v1 = l2[b * 3 + 1], l2v2 = l2[b * 3 + 2];

  int pl = (w << 4) + l15;
  float muv = mu2[(b << 16) + n0 + pl];
  float rsv = rs2[(b << 16) + n0 + pl];
  short8 xf[2];
  #pragma unroll
  for (int ks = 0; ks < 2; ++ks)
    #pragma unroll
    for (int i = 0; i < 8; ++i) {
      int c = (ks << 5) + (g << 3) + i;
      float v = (T[c * 129 + pl] - muv) * rsv * lw[c] + lb[c];
      xf[ks][i] = (short)f2bs(v);
    }

  f32x4 acc2[4] = {{0,0,0,0},{0,0,0,0},{0,0,0,0},{0,0,0,0}};
  short* HsW = &Hs[w][0];

  #pragma unroll 1
  for (int ch = 0; ch < 7; ++ch) {
    int jbase = ch << 6;
    float le = (ch == 0) ? l2v0 : (ch < 3 ? l2v1 : l2v2);
    #pragma unroll
    for (int nt = 0; nt < 4; ++nt) {
      int jl = jbase + (nt << 4) + l15;
      short8 bf0 = *(const short8*)(w1b + (jl << 6) + (g << 3));
      short8 bf1 = *(const short8*)(w1b + (jl << 6) + 32 + (g << 3));
      f32x4 a1 = {0.f, 0.f, 0.f, 0.f};
      a1 = __builtin_amdgcn_mfma_f32_16x16x32_bf16(bf0, xf[0], a1, 0, 0, 0); // D[j][p]
      a1 = __builtin_amdgcn_mfma_f32_16x16x32_bf16(bf1, xf[1], a1, 0, 0, 0);
      f32x4 b1v = *(const f32x4*)(b1f + jbase + (nt << 4) + (g << 2));
      short4 hp;
      #pragma unroll
      for (int r = 0; r < 4; ++r) {
        float tv = a1[r] + b1v[r];
        float uu = tv * (0.7978845608f + 0.0356774081f * tv * tv);
        float gv = le * __fdividef(tv, 1.f + __expf(-2.f * uu));  // tanh-gelu
        ((short*)&hp)[r] = (short)f2bs(gv);
      }
      // lane: col p = l15, rows j = 16nt + 4g + r  ->  Hs[p][j] contiguous
      *(short4*)(HsW + l15 * 80 + (nt << 4) + (g << 2)) = hp;
    }
    __builtin_amdgcn_s_waitcnt(0);
    #pragma unroll
    for (int kt = 0; kt < 2; ++kt) {
      short8 af = *(const short8*)(HsW + l15 * 80 + (kt << 5) + (g << 3));
      #pragma unroll
      for (int ot = 0; ot < 4; ++ot) {
        short8 bf = *(const short8*)(w2b + (((ot << 4) + l15) * 448) + jbase + (kt << 5) + (g << 3));
        acc2[ot] = __builtin_amdgcn_mfma_f32_16x16x32_bf16(af, bf, acc2[ot], 0, 0, 0);
      }
    }
  }

  #pragma unroll
  for (int ot = 0; ot < 4; ++ot) {
    int o = (ot << 4) + l15;
    float bias = l2v0 * b2_0[o] + l2v1 * b2_1[o] + l2v2 * b2_2[o];
    float gmv = gamma[o];
    #pragma unroll
    for (int r = 0; r < 4; ++r) {
      int p = (w << 4) + (g << 2) + r;
      float* tp = &T[o * 129 + p];
      *tp = acc2[ot][r] + gmv * (*tp) + bias;
    }
  }
  __syncthreads();

  for (int i = 0; i < 16; ++i) {
    int idx = i * 512 + t;
    int c = idx >> 7, p = idx & 127;
    io[iob + ((size_t)c << 16) + p] = T[c * 129 + p];
  }
}

extern "C" void kernel_launch(void* const* d_in, const int* in_sizes, int n_in,
                              void* d_out, int out_size, void* d_ws, size_t ws_size,
                              hipStream_t stream) {
  (void)in_sizes; (void)n_in; (void)out_size; (void)ws_size;
  const float* x        = (const float*)d_in[0];
  const float* hidden   = (const float*)d_in[1];
  const float* ln1_w    = (const float*)d_in[2];
  const float* ln1_b    = (const float*)d_in[3];
  const float* ln2_w    = (const float*)d_in[4];
  const float* ln2_b    = (const float*)d_in[5];
  const float* beta     = (const float*)d_in[6];
  const float* gamma    = (const float*)d_in[7];
  const float* att_temp = (const float*)d_in[8];
  const float* att_qkv  = (const float*)d_in[9];
  const float* att_dw   = (const float*)d_in[10];
  const float* att_proj = (const float*)d_in[11];
  const float* ar1_w    = (const float*)d_in[12];
  const float* ar1_b    = (const float*)d_in[13];
  const float* ar3_w    = (const float*)d_in[14];
  const float* ar3_b    = (const float*)d_in[15];
  const float* mr1_w    = (const float*)d_in[16];
  const float* mr1_b    = (const float*)d_in[17];
  const float* mr3_w    = (const float*)d_in[18];
  const float* mr3_b    = (const float*)d_in[19];
  const float* w1s[3] = {(const float*)d_in[20], (const float*)d_in[24], (const float*)d_in[28]};
  const float* b1s[3] = {(const float*)d_in[21], (const float*)d_in[25], (const float*)d_in[29]};
  const float* w2s[3] = {(const float*)d_in[22], (const float*)d_in[26], (const float*)d_in[30]};
  const float* b2s[3] = {(const float*)d_in[23], (const float*)d_in[27], (const float*)d_in[31]};

  // ---- workspace (~4.9 MB fp32) ----
  float* F    = (float*)d_ws;
  float* mu1  = F + 0;          // 262144
  float* rs1  = F + 262144;     // 262144
  float* mu2  = F + 524288;     // 262144
  float* rs2  = F + 786432;     // 262144
  float* M    = F + 1048576;    // 16384 ┐
  float* xg1s = F + 1064960;    // 256   ├ zeroed together (16896)
  float* xg2s = F + 1065216;    // 256   ┘
  float* h1a  = F + 1065472;    // 64
  float* h1m  = F + 1065536;    // 64
  float* l1   = F + 1065600;    // 16
  float* l2   = F + 1065616;    // 16
  float* Weff = F + 1065632;    // 49152
  unsigned short* Ktb = (unsigned short*)(F + 1114784);  // 147456 ushorts
  float* b1f  = F + 1188512;    // 448
  unsigned short* w1b = (unsigned short*)(F + 1188960);  // 28672 ushorts
  unsigned short* w2b = (unsigned short*)(F + 1203296);  // 28672 ushorts

  float* out_main   = (float*)d_out;             // holds out1 between banks
  float* out_hidden = out_main + 16777216;
  float* out_logits = out_main + 16777280;

  // ---- attention bank ----
  k_zero   <<<66, 256, 0, stream>>>(M, 16896);   // M + xg1s + xg2s
  k_statsxg<<<1024, 256, 0, stream>>>(x, mu1, rs1, ln1_w, ln1_b, xg1s, M);
  k_route  <<<1, 64, 0, stream>>>(xg1s, hidden, ar1_w, ar1_b, ar3_w, ar3_b,
                                  h1a, l1, out_logits, 0, nullptr);
  k_expw   <<<12, 256, 0, stream>>>(M, att_qkv, att_temp, Weff);
  k_kmat   <<<36, 256, 0, stream>>>(Weff, att_dw, att_proj, l1, Ktb);
  k_conv   <<<dim3(16, 16, 4), 256, 0, stream>>>(x, mu1, rs1, ln1_w, ln1_b, Ktb,
                                                 beta, out_main, ln2_w, ln2_b,
                                                 mu2, rs2, xg2s);
  // ---- MLP bank (out1 lives in d_out) ----
  k_route  <<<1, 64, 0, stream>>>(xg2s, h1a, mr1_w, mr1_b, mr3_w, mr3_b,
                                  h1m, l2, out_logits, 1, out_hidden);
  k_prep   <<<112, 256, 0, stream>>>(w1s[0], w1s[1], w1s[2], b1s[0], b1s[1], b1s[2],
                                     w2s[0], w2s[1], w2s[2], w1b, w2b, b1f);
  k_mlp    <<<2048, 512, 0, stream>>>(out_main, mu2, rs2, ln2_w, ln2_b,
                                      w1b, w2b, b1f, b2s[0], b2s[1], b2s[2],
                                      gamma, l2);
}

// Round 7
// 432.594 us; speedup vs baseline: 4.3102x; 1.1999x over previous
//
#include <hip/hip_runtime.h>
#include <hip/hip_bf16.h>
#include <cstddef>

typedef __attribute__((ext_vector_type(8))) short short8;
typedef __attribute__((ext_vector_type(4))) float f32x4;

#define NPIX 65536  // 256*256

static __device__ __forceinline__ unsigned short f2bs(float f) {
  union { float f; unsigned u; } v; v.f = f;
  unsigned r = (v.u + 0x7FFFu + ((v.u >> 16) & 1u)) >> 16;
  return (unsigned short)r;
}
static __device__ __forceinline__ float s2f(short s) {
  union { unsigned u; float f; } v; v.u = ((unsigned)(unsigned short)s) << 16;
  return v.f;
}

__global__ void k_zero(float* __restrict__ p, int n) {
  int i = blockIdx.x * 256 + threadIdx.x;
  if (i < n) p[i] = 0.f;
}

// ---- fused bank-1 pre-pass: mu1/rs1 per pixel, xg1 channel sums, Gram M (MFMA) ----
__global__ __launch_bounds__(256, 4)
void k_statsxg(const float* __restrict__ in, float* __restrict__ mu,
               float* __restrict__ rs, const float* __restrict__ lnw,
               const float* __restrict__ lnb, float* __restrict__ Ssum,
               float* __restrict__ M) {
  __shared__ __align__(16) short tile[64 * 264];   // [c][256 px + pad]
  __shared__ float wred[4][64];
  int t = threadIdx.x;
  int pi = blockIdx.x * 256 + t;
  int b = blockIdx.x >> 8;
  const float* p = in + ((size_t)b << 22) + (pi & 65535);
  float s = 0.f, s2 = 0.f;
  #pragma unroll
  for (int c = 0; c < 64; ++c) {
    float v = p[(size_t)c << 16];
    s += v; s2 += v * v;
    tile[c * 264 + t] = (short)f2bs(v);
  }
  float m = s * 0.015625f;
  float var = s2 * 0.015625f - m * m;
  float rstd = rsqrtf(var + 1e-5f);
  mu[pi] = m; rs[pi] = rstd;
  int l = t & 63, w = t >> 6, l15 = l & 15, g = l >> 4;
  for (int c = 0; c < 64; ++c) {
    float lnv = (s2f(tile[c * 264 + t]) - m) * rstd * lnw[c] + lnb[c];
    tile[c * 264 + t] = (short)f2bs(lnv);          // own column only
    float r = lnv;
    #pragma unroll
    for (int o = 32; o > 0; o >>= 1) r += __shfl_down(r, o, 64);
    if (l == 0) wred[w][c] = r;
  }
  __syncthreads();
  if (t < 64)
    atomicAdd(&Ssum[b * 64 + t],
              wred[0][t] + wred[1][t] + wred[2][t] + wred[3][t]);
  // Gram: wave w computes rows 16w..16w+15 x all 64 cols, K = 256 px
  f32x4 ga[4] = {{0,0,0,0},{0,0,0,0},{0,0,0,0},{0,0,0,0}};
  #pragma unroll
  for (int kt = 0; kt < 8; ++kt) {
    short8 af = *(const short8*)(tile + (16 * w + l15) * 264 + (kt << 5) + (g << 3));
    #pragma unroll
    for (int ot = 0; ot < 4; ++ot) {
      short8 bfg = *(const short8*)(tile + ((ot << 4) + l15) * 264 + (kt << 5) + (g << 3));
      ga[ot] = __builtin_amdgcn_mfma_f32_16x16x32_bf16(af, bfg, ga[ot], 0, 0, 0);
    }
  }
  float* Mb = M + b * 4096;
  #pragma unroll
  for (int ot = 0; ot < 4; ++ot)
    #pragma unroll
    for (int r = 0; r < 4; ++r)
      atomicAdd(&Mb[(16 * w + (g << 2) + r) * 64 + (ot << 4) + l15], ga[ot][r]);
}

// ---------------- routing ----------------
__global__ void k_route(const float* __restrict__ Ssum, const float* __restrict__ hid,
                        const float* __restrict__ w1, const float* __restrict__ b1,
                        const float* __restrict__ w3, const float* __restrict__ b3,
                        float* __restrict__ h1_out, float* __restrict__ logit_out,
                        float* __restrict__ out_logits, int slot,
                        float* __restrict__ out_hidden) {
  __shared__ float xgs[4][64];
  __shared__ float h1s[4][16];
  int t = threadIdx.x;                             // 64 threads
  for (int i = t; i < 256; i += 64)
    xgs[i >> 6][i & 63] = Ssum[i] * (1.f / 65536.f);
  __syncthreads();
  {
    int b = t >> 4, j = t & 15;
    float a = b1[j];
    for (int c = 0; c < 64; ++c) a += w1[j * 80 + c] * xgs[b][c];
    for (int k = 0; k < 16; ++k) a += w1[j * 80 + 64 + k] * hid[b * 16 + k];
    float g = 0.5f * a * (1.f + erff(a * 0.70710678f));   // exact gelu
    h1s[b][j] = g;
    h1_out[b * 16 + j] = g;
    if (out_hidden) out_hidden[b * 16 + j] = g;
  }
  __syncthreads();
  if (t < 12) {
    int b = t / 3, e = t % 3;
    float a = b3[e];
    for (int j = 0; j < 16; ++j) a += w3[e * 16 + j] * h1s[b][j];
    a = fmaxf(a, 0.f);
    logit_out[b * 3 + e] = a;
    out_logits[b * 6 + e * 2 + slot] = a;
  }
}

// ---------------- per (b,expert): softmax(q̂·k̂·temp) -> Weff = P @ Wv ----------------
__global__ void k_expw(const float* __restrict__ M, const float* __restrict__ qkv,
                       const float* __restrict__ temp, float* __restrict__ Weff) {
  int b = blockIdx.x / 3, e = blockIdx.x % 3;
  __shared__ float Ms[64][64];
  __shared__ float TQ[64][64];
  __shared__ float TK[64][64];
  __shared__ float P[64][4];
  __shared__ float nq[64], nk[64];
  const float* W = qkv + e * 12288;
  for (int idx = threadIdx.x; idx < 4096; idx += 256)
    Ms[idx >> 6][idx & 63] = M[b * 4096 + idx];
  __syncthreads();
  {
    int r = threadIdx.x >> 2;
    int v0 = (threadIdx.x & 3) << 4;
    float aq[16] = {}, ak[16] = {};
    for (int u = 0; u < 64; ++u) {
      float wq = W[r * 64 + u];
      float wk = W[(64 + r) * 64 + u];
      #pragma unroll
      for (int i = 0; i < 16; ++i) {
        float m = Ms[u][v0 + i];
        aq[i] += wq * m; ak[i] += wk * m;
      }
    }
    #pragma unroll
    for (int i = 0; i < 16; ++i) { TQ[r][v0 + i] = aq[i]; TK[r][v0 + i] = ak[i]; }
  }
  __syncthreads();
  if (threadIdx.x < 64) {
    int c = threadIdx.x;
    float sq = 0.f, sk = 0.f;
    for (int v = 0; v < 64; ++v) {
      sq += TQ[c][v] * W[c * 64 + v];
      sk += TK[c][v] * W[(64 + c) * 64 + v];
    }
    nq[c] = fmaxf(sqrtf(fmaxf(sq, 0.f)), 1e-12f);
    nk[c] = fmaxf(sqrtf(fmaxf(sk, 0.f)), 1e-12f);
  }
  __syncthreads();
  if (threadIdx.x < 64) {
    int rr = threadIdx.x, h = rr >> 2;
    float tp = temp[e * 16 + h];
    float s[4];
    #pragma unroll
    for (int d = 0; d < 4; ++d) {
      int kc = h * 4 + d;
      float g = 0.f;
      for (int v = 0; v < 64; ++v) g += TQ[rr][v] * W[(64 + kc) * 64 + v];
      s[d] = g / (nq[rr] * nk[kc]) * tp;
    }
    float mx = fmaxf(fmaxf(s[0], s[1]), fmaxf(s[2], s[3]));
    float es[4], sum = 0.f;
    #pragma unroll
    for (int d = 0; d < 4; ++d) { es[d] = __expf(s[d] - mx); sum += es[d]; }
    float inv = 1.f / sum;
    #pragma unroll
    for (int d = 0; d < 4; ++d) P[rr][d] = es[d] * inv;
  }
  __syncthreads();
  if (threadIdx.x < 64) {
    int rr = threadIdx.x, h = rr >> 2;
    for (int u = 0; u < 64; ++u) {
      float a = 0.f;
      #pragma unroll
      for (int d = 0; d < 4; ++d)
        a += P[rr][d] * W[(128 + h * 4 + d) * 64 + u];
      Weff[(size_t)(b * 3 + e) * 4096 + rr * 64 + u] = a;
    }
  }
}

// ------ Ktb[b][tap][o][u] = bf16( Σ_e l1_e Proj_e[o,c] dw_e[c,tap] Weff_e[c,u] ) ------
__global__ void k_kmat(const float* __restrict__ Weff, const float* __restrict__ dw,
                       const float* __restrict__ proj, const float* __restrict__ l1,
                       unsigned short* __restrict__ Ktb) {
  int b = blockIdx.x / 9, t = blockIdx.x % 9;
  __shared__ float S[64][68];
  __shared__ float Pr[64][68];
  int u = threadIdx.x >> 2, o0 = (threadIdx.x & 3) << 4;
  float acc[16] = {};
  for (int e = 0; e < 3; ++e) {
    __syncthreads();
    float le = l1[b * 3 + e];
    for (int idx = threadIdx.x; idx < 4096; idx += 256) {
      int c = idx >> 6, uu = idx & 63;
      S[c][uu] = le * dw[(e * 64 + c) * 9 + t] *
                 Weff[(size_t)(b * 3 + e) * 4096 + c * 64 + uu];
      Pr[c][uu] = proj[e * 4096 + uu * 64 + c];
    }
    __syncthreads();
    for (int c = 0; c < 64; ++c) {
      float sv = S[c][u];
      #pragma unroll
      for (int i = 0; i < 16; ++i) acc[i] += Pr[c][o0 + i] * sv;
    }
  }
  #pragma unroll
  for (int i = 0; i < 16; ++i)
    Ktb[(size_t)(b * 9 + t) * 4096 + (o0 + i) * 64 + u] = f2bs(acc[i]);
}

// -------- MFMA conv + residual + fused LN2 stats + xg2 sums --------
__global__ __launch_bounds__(256, 3)
void k_conv(const float* __restrict__ x, const float* __restrict__ mu,
            const float* __restrict__ rs, const float* __restrict__ lw,
            const float* __restrict__ lb, const unsigned short* __restrict__ Ktb,
            const float* __restrict__ beta, float* __restrict__ out1,
            const float* __restrict__ lw2, const float* __restrict__ lb2,
            float* __restrict__ mu2, float* __restrict__ rs2,
            float* __restrict__ Ssum2) {
  __shared__ __align__(16) short lds[20736];     // halo, then result [o][260]
  __shared__ float wred[4][64];

  int x0 = blockIdx.x << 4, y0 = blockIdx.y << 4, b = blockIdx.z;

  for (int idx = threadIdx.x; idx < 20736; idx += 256) {
    int c = idx / 324, hpix = idx - c * 324;
    int hy = hpix / 18, hx = hpix - hy * 18;
    int gy = y0 + hy - 1, gx = x0 + hx - 1;
    float v = 0.f;
    if ((unsigned)gy < 256u && (unsigned)gx < 256u) {
      int n = (gy << 8) + gx;
      float xv = x[((size_t)(b * 64 + c) << 16) + n];
      v = (xv - mu[(b << 16) + n]) * rs[(b << 16) + n] * lw[c] + lb[c];
    }
    lds[hpix * 64 + ((((c >> 3) ^ (hpix & 7)) << 3) | (c & 7))] = (short)f2bs(v);
  }
  __syncthreads();

  int w = threadIdx.x >> 6, l = threadIdx.x & 63;
  int l15 = l & 15, g = l >> 4;

  f32x4 acc[4][4] = {};
  const unsigned short* Kb = Ktb + (size_t)b * 9 * 4096;

  #pragma unroll 1
  for (int tap = 0; tap < 9; ++tap) {
    int ky = tap / 3, kx = tap - ky * 3;
    const unsigned short* Kt = Kb + (tap << 12);
    #pragma unroll
    for (int ks = 0; ks < 2; ++ks) {
      short8 bfr[4];
      #pragma unroll
      for (int ot = 0; ot < 4; ++ot)
        bfr[ot] = *(const short8*)(Kt + (((ot << 4) + l15) << 6) + (ks << 5) + (g << 3));
      int blk = ((ks << 2) | g);
      #pragma unroll
      for (int mi = 0; mi < 4; ++mi) {
        int hpix = ((w << 2) + mi + ky) * 18 + l15 + kx;
        short8 af = *(const short8*)(lds + hpix * 64 + ((blk ^ (hpix & 7)) << 3));
        #pragma unroll
        for (int ot = 0; ot < 4; ++ot)
          acc[mi][ot] = __builtin_amdgcn_mfma_f32_16x16x32_bf16(af, bfr[ot], acc[mi][ot], 0, 0, 0);
      }
    }
  }

  __syncthreads();                               // reuse lds as Rs[o][260]
  #pragma unroll
  for (int mi = 0; mi < 4; ++mi) {
    int p0 = (((w << 2) + mi) << 4) + (g << 2);
    #pragma unroll
    for (int ot = 0; ot < 4; ++ot) {
      int o = (ot << 4) + l15;
      short4 pk;
      pk.x = (short)f2bs(acc[mi][ot][0]);
      pk.y = (short)f2bs(acc[mi][ot][1]);
      pk.z = (short)f2bs(acc[mi][ot][2]);
      pk.w = (short)f2bs(acc[mi][ot][3]);
      *(short4*)(lds + o * 260 + p0) = pk;
    }
  }
  __syncthreads();

  // residual + store + LN2 stats (thread owns pixel p2)
  int p2 = threadIdx.x;
  int n = ((y0 + (p2 >> 4)) << 8) + x0 + (p2 & 15);
  float s = 0.f, s2 = 0.f;
  #pragma unroll
  for (int c = 0; c < 64; ++c) {
    size_t gi = ((size_t)(b * 64 + c) << 16) + n;
    float v = s2f(lds[c * 260 + p2]) + beta[c] * x[gi];
    out1[gi] = v;
    s += v; s2 += v * v;
    lds[c * 260 + p2] = (short)f2bs(v);          // own column only
  }
  float m = s * 0.015625f;
  float var = s2 * 0.015625f - m * m;
  float rstd = rsqrtf(var + 1e-5f);
  mu2[(b << 16) + n] = m;
  rs2[(b << 16) + n] = rstd;
  for (int c = 0; c < 64; ++c) {
    float lnv = (s2f(lds[c * 260 + p2]) - m) * rstd * lw2[c] + lb2[c];
    #pragma unroll
    for (int o = 32; o > 0; o >>= 1) lnv += __shfl_down(lnv, o, 64);
    if (l == 0) wred[w][c] = lnv;
  }
  __syncthreads();
  if (threadIdx.x < 64)
    atomicAdd(&Ssum2[b * 64 + threadIdx.x],
              wred[0][threadIdx.x] + wred[1][threadIdx.x] +
              wred[2][threadIdx.x] + wred[3][threadIdx.x]);
}

// ---------------- prep MLP weights as bf16: w1b[jt][c], w2b[o][jt], b1f[jt] ----------------
__global__ void k_prep(const float* __restrict__ w1_0, const float* __restrict__ w1_1,
                       const float* __restrict__ w1_2,
                       const float* __restrict__ b1_0, const float* __restrict__ b1_1,
                       const float* __restrict__ b1_2,
                       const float* __restrict__ w2_0, const float* __restrict__ w2_1,
                       const float* __restrict__ w2_2,
                       unsigned short* __restrict__ w1b, unsigned short* __restrict__ w2b,
                       float* __restrict__ b1f) {
  int idx = blockIdx.x * 256 + threadIdx.x;
  if (idx >= 448 * 64) return;
  int jt = idx >> 6, c = idx & 63;
  int e, j;
  if (jt < 64)       { e = 0; j = jt; }
  else if (jt < 192) { e = 1; j = jt - 64; }
  else               { e = 2; j = jt - 192; }
  const float* w1 = e == 0 ? w1_0 : (e == 1 ? w1_1 : w1_2);
  const float* w2 = e == 0 ? w2_0 : (e == 1 ? w2_1 : w2_2);
  int hf = 64 << e;
  w1b[jt * 64 + c]  = f2bs(w1[j * 64 + c]);
  w2b[c * 448 + jt] = f2bs(w2[c * hf + j]);
  if (c == 0) {
    const float* b1 = e == 0 ? b1_0 : (e == 1 ? b1_1 : b1_2);
    b1f[jt] = b1[j];
  }
}

// ---------------- MFMA fused MLP bank, all-register H (no LDS round-trip) ----------------
// 256 thr (4 waves), 128 px/block, 32 px/wave (2 pixel-frags).
// GEMM1 A-rows permuted (jl = 8*(l15>>2)+(l15&3)+4q) so the two gelu'd f32x4
// outputs concatenate into a K=32 A-frag (k = 8g+i) for GEMM2 directly.
__global__ __launch_bounds__(256, 4)
void k_mlp(float* io,
           const float* __restrict__ mu2, const float* __restrict__ rs2,
           const float* __restrict__ lw, const float* __restrict__ lb,
           const unsigned short* __restrict__ w1b, const unsigned short* __restrict__ w2b,
           const float* __restrict__ b1f,
           const float* __restrict__ b2_0, const float* __restrict__ b2_1,
           const float* __restrict__ b2_2,
           const float* __restrict__ gamma, const float* __restrict__ l2) {
  __shared__ float T[64 * 129];                  // io tile [c][128 px + pad]

  int b  = blockIdx.x >> 9;
  int n0 = (blockIdx.x & 511) << 7;
  int t  = threadIdx.x;
  int w  = t >> 6, l = t & 63;
  int l15 = l & 15, g = l >> 4;

  size_t iob = ((size_t)b << 22) + n0;
  for (int i = 0; i < 32; ++i) {
    int idx = i * 256 + t;
    int c = idx >> 7, p = idx & 127;
    T[c * 129 + p] = io[iob + ((size_t)c << 16) + p];
  }
  __syncthreads();

  float l2v0 = l2[b * 3], l2v1 = l2[b * 3 + 1], l2v2 = l2[b * 3 + 2];

  // X B-frags (col = pixel, k = channel 8g+i), LN applied; 2 pixel-frags/wave
  short8 xf[2][2];
  #pragma unroll
  for (int pf = 0; pf < 2; ++pf) {
    int pl = (w << 5) + (pf << 4) + l15;
    float muv = mu2[(b << 16) + n0 + pl];
    float rsv = rs2[(b << 16) + n0 + pl];
    #pragma unroll
    for (int ks = 0; ks < 2; ++ks)
      #pragma unroll
      for (int i = 0; i < 8; ++i) {
        int c = (ks << 5) + (g << 3) + i;
        float v = (T[c * 129 + pl] - muv) * rsv * lw[c] + lb[c];
        xf[pf][ks][i] = (short)f2bs(v);
      }
  }

  int jrow = ((l15 >> 2) << 3) + (l15 & 3);      // permuted W1 row for this lane

  f32x4 acc2[2][4] = {{{0,0,0,0},{0,0,0,0},{0,0,0,0},{0,0,0,0}},
                      {{0,0,0,0},{0,0,0,0},{0,0,0,0},{0,0,0,0}}};

  #pragma unroll 2
  for (int jb = 0; jb < 14; ++jb) {              // 32 j per iteration
    int j0 = jb << 5;
    float le = (jb < 2) ? l2v0 : (jb < 6 ? l2v1 : l2v2);
    short8 w1a[2][2];
    f32x4 b1v[2];
    #pragma unroll
    for (int q = 0; q < 2; ++q) {
      int jt = j0 + jrow + (q << 2);
      w1a[q][0] = *(const short8*)(w1b + (jt << 6) + (g << 3));
      w1a[q][1] = *(const short8*)(w1b + (jt << 6) + 32 + (g << 3));
      b1v[q] = *(const f32x4*)(b1f + j0 + (g << 3) + (q << 2));
    }
    short8 A2[2];
    #pragma unroll
    for (int pf = 0; pf < 2; ++pf) {
      #pragma unroll
      for (int q = 0; q < 2; ++q) {
        f32x4 d1 = {0.f, 0.f, 0.f, 0.f};
        d1 = __builtin_amdgcn_mfma_f32_16x16x32_bf16(w1a[q][0], xf[pf][0], d1, 0, 0, 0);
        d1 = __builtin_amdgcn_mfma_f32_16x16x32_bf16(w1a[q][1], xf[pf][1], d1, 0, 0, 0);
        #pragma unroll
        for (int r = 0; r < 4; ++r) {            // lane holds j = j0 + 8g + 4q + r
          float tv = d1[r] + b1v[q][r];
          float uu = tv * (0.7978845608f + 0.0356774081f * tv * tv);
          float gv = le * __fdividef(tv, 1.f + __expf(-2.f * uu));  // tanh-gelu
          A2[pf][(q << 2) + r] = (short)f2bs(gv);
        }
      }
    }
    #pragma unroll
    for (int ot = 0; ot < 4; ++ot) {
      short8 w2f = *(const short8*)(w2b + (((ot << 4) + l15) * 448) + j0 + (g << 3));
      acc2[0][ot] = __builtin_amdgcn_mfma_f32_16x16x32_bf16(A2[0], w2f, acc2[0][ot], 0, 0, 0);
      acc2[1][ot] = __builtin_amdgcn_mfma_f32_16x16x32_bf16(A2[1], w2f, acc2[1][ot], 0, 0, 0);
    }
  }

  // epilogue: acc2 + gamma*o1 + sum l2_e*b2_e into T (own pixel strip)
  #pragma unroll
  for (int ot = 0; ot < 4; ++ot) {
    int o = (ot << 4) + l15;
    float bias = l2v0 * b2_0[o] + l2v1 * b2_1[o] + l2v2 * b2_2[o];
    float gmv = gamma[o];
    #pragma unroll
    for (int pf = 0; pf < 2; ++pf)
      #pragma unroll
      for (int r = 0; r < 4; ++r) {
        int p = (w << 5) + (pf << 4) + (g << 2) + r;
        float* tp = &T[o * 129 + p];
        *tp = acc2[pf][ot][r] + gmv * (*tp) + bias;
      }
  }
  __syncthreads();

  for (int i = 0; i < 32; ++i) {
    int idx = i * 256 + t;
    int c = idx >> 7, p = idx & 127;
    io[iob + ((size_t)c << 16) + p] = T[c * 129 + p];
  }
}

extern "C" void kernel_launch(void* const* d_in, const int* in_sizes, int n_in,
                              void* d_out, int out_size, void* d_ws, size_t ws_size,
                              hipStream_t stream) {
  (void)in_sizes; (void)n_in; (void)out_size; (void)ws_size;
  const float* x        = (const float*)d_in[0];
  const float* hidden   = (const float*)d_in[1];
  const float* ln1_w    = (const float*)d_in[2];
  const float* ln1_b    = (const float*)d_in[3];
  const float* ln2_w    = (const float*)d_in[4];
  const float* ln2_b    = (const float*)d_in[5];
  const float* beta     = (const float*)d_in[6];
  const float* gamma    = (const float*)d_in[7];
  const float* att_temp = (const float*)d_in[8];
  const float* att_qkv  = (const float*)d_in[9];
  const float* att_dw   = (const float*)d_in[10];
  const float* att_proj = (const float*)d_in[11];
  const float* ar1_w    = (const float*)d_in[12];
  const float* ar1_b    = (const float*)d_in[13];
  const float* ar3_w    = (const float*)d_in[14];
  const float* ar3_b    = (const float*)d_in[15];
  const float* mr1_w    = (const float*)d_in[16];
  const float* mr1_b    = (const float*)d_in[17];
  const float* mr3_w    = (const float*)d_in[18];
  const float* mr3_b    = (const float*)d_in[19];
  const float* w1s[3] = {(const float*)d_in[20], (const float*)d_in[24], (const float*)d_in[28]};
  const float* b1s[3] = {(const float*)d_in[21], (const float*)d_in[25], (const float*)d_in[29]};
  const float* w2s[3] = {(const float*)d_in[22], (const float*)d_in[26], (const float*)d_in[30]};
  const float* b2s[3] = {(const float*)d_in[23], (const float*)d_in[27], (const float*)d_in[31]};

  // ---- workspace (~4.9 MB fp32) ----
  float* F    = (float*)d_ws;
  float* mu1  = F + 0;          // 262144
  float* rs1  = F + 262144;     // 262144
  float* mu2  = F + 524288;     // 262144
  float* rs2  = F + 786432;     // 262144
  float* M    = F + 1048576;    // 16384 ┐
  float* xg1s = F + 1064960;    // 256   ├ zeroed together (16896)
  float* xg2s = F + 1065216;    // 256   ┘
  float* h1a  = F + 1065472;    // 64
  float* h1m  = F + 1065536;    // 64
  float* l1   = F + 1065600;    // 16
  float* l2   = F + 1065616;    // 16
  float* Weff = F + 1065632;    // 49152
  unsigned short* Ktb = (unsigned short*)(F + 1114784);  // 147456 ushorts
  float* b1f  = F + 1188512;    // 448
  unsigned short* w1b = (unsigned short*)(F + 1188960);  // 28672 ushorts
  unsigned short* w2b = (unsigned short*)(F + 1203296);  // 28672 ushorts

  float* out_main   = (float*)d_out;             // holds out1 between banks
  float* out_hidden = out_main + 16777216;
  float* out_logits = out_main + 16777280;

  // ---- attention bank ----
  k_zero   <<<66, 256, 0, stream>>>(M, 16896);   // M + xg1s + xg2s
  k_statsxg<<<1024, 256, 0, stream>>>(x, mu1, rs1, ln1_w, ln1_b, xg1s, M);
  k_route  <<<1, 64, 0, stream>>>(xg1s, hidden, ar1_w, ar1_b, ar3_w, ar3_b,
                                  h1a, l1, out_logits, 0, nullptr);
  k_expw   <<<12, 256, 0, stream>>>(M, att_qkv, att_temp, Weff);
  k_kmat   <<<36, 256, 0, stream>>>(Weff, att_dw, att_proj, l1, Ktb);
  k_conv   <<<dim3(16, 16, 4), 256, 0, stream>>>(x, mu1, rs1, ln1_w, ln1_b, Ktb,
                                                 beta, out_main, ln2_w, ln2_b,
                                                 mu2, rs2, xg2s);
  // ---- MLP bank (out1 lives in d_out) ----
  k_route  <<<1, 64, 0, stream>>>(xg2s, h1a, mr1_w, mr1_b, mr3_w, mr3_b,
                                  h1m, l2, out_logits, 1, out_hidden);
  k_prep   <<<112, 256, 0, stream>>>(w1s[0], w1s[1], w1s[2], b1s[0], b1s[1], b1s[2],
                                     w2s[0], w2s[1], w2s[2], w1b, w2b, b1f);
  k_mlp    <<<2048, 256, 0, stream>>>(out_main, mu2, rs2, ln2_w, ln2_b,
                                      w1b, w2b, b1f, b2s[0], b2s[1], b2s[2],
                                      gamma, l2);
}

// Round 8
// 401.448 us; speedup vs baseline: 4.6446x; 1.0776x over previous
//
#include <hip/hip_runtime.h>
#include <hip/hip_bf16.h>
#include <cstddef>

typedef __attribute__((ext_vector_type(8))) short short8;
typedef __attribute__((ext_vector_type(4))) float f32x4;

#define NPIX 65536  // 256*256

static __device__ __forceinline__ unsigned short f2bs(float f) {
  union { float f; unsigned u; } v; v.f = f;
  unsigned r = (v.u + 0x7FFFu + ((v.u >> 16) & 1u)) >> 16;
  return (unsigned short)r;
}
static __device__ __forceinline__ float s2f(short s) {
  union { unsigned u; float f; } v; v.u = ((unsigned)(unsigned short)s) << 16;
  return v.f;
}

__global__ void k_zero(float* __restrict__ p, int n) {
  int i = blockIdx.x * 256 + threadIdx.x;
  if (i < n) p[i] = 0.f;
}

// ---- fused bank-1 pre-pass: mu1/rs1 per pixel, xg1 channel sums, Gram M (MFMA) ----
__global__ __launch_bounds__(256, 4)
void k_statsxg(const float* __restrict__ in, float* __restrict__ mu,
               float* __restrict__ rs, const float* __restrict__ lnw,
               const float* __restrict__ lnb, float* __restrict__ Ssum,
               float* __restrict__ M) {
  __shared__ __align__(16) short tile[64 * 264];   // [c][256 px + pad]
  __shared__ float wred[4][64];
  int t = threadIdx.x;
  int pi = blockIdx.x * 256 + t;
  int b = blockIdx.x >> 8;
  const float* p = in + ((size_t)b << 22) + (pi & 65535);
  float s = 0.f, s2 = 0.f;
  #pragma unroll
  for (int c = 0; c < 64; ++c) {
    float v = p[(size_t)c << 16];
    s += v; s2 += v * v;
    tile[c * 264 + t] = (short)f2bs(v);
  }
  float m = s * 0.015625f;
  float var = s2 * 0.015625f - m * m;
  float rstd = rsqrtf(var + 1e-5f);
  mu[pi] = m; rs[pi] = rstd;
  int l = t & 63, w = t >> 6, l15 = l & 15, g = l >> 4;
  for (int c = 0; c < 64; ++c) {
    float lnv = (s2f(tile[c * 264 + t]) - m) * rstd * lnw[c] + lnb[c];
    tile[c * 264 + t] = (short)f2bs(lnv);          // own column only
    float r = lnv;
    #pragma unroll
    for (int o = 32; o > 0; o >>= 1) r += __shfl_down(r, o, 64);
    if (l == 0) wred[w][c] = r;
  }
  __syncthreads();
  if (t < 64)
    atomicAdd(&Ssum[b * 64 + t],
              wred[0][t] + wred[1][t] + wred[2][t] + wred[3][t]);
  // Gram: wave w computes rows 16w..16w+15 x all 64 cols, K = 256 px
  f32x4 ga[4] = {{0,0,0,0},{0,0,0,0},{0,0,0,0},{0,0,0,0}};
  #pragma unroll
  for (int kt = 0; kt < 8; ++kt) {
    short8 af = *(const short8*)(tile + (16 * w + l15) * 264 + (kt << 5) + (g << 3));
    #pragma unroll
    for (int ot = 0; ot < 4; ++ot) {
      short8 bfg = *(const short8*)(tile + ((ot << 4) + l15) * 264 + (kt << 5) + (g << 3));
      ga[ot] = __builtin_amdgcn_mfma_f32_16x16x32_bf16(af, bfg, ga[ot], 0, 0, 0);
    }
  }
  float* Mb = M + b * 4096;
  #pragma unroll
  for (int ot = 0; ot < 4; ++ot)
    #pragma unroll
    for (int r = 0; r < 4; ++r)
      atomicAdd(&Mb[(16 * w + (g << 2) + r) * 64 + (ot << 4) + l15], ga[ot][r]);
}

// ---------------- routing ----------------
__global__ void k_route(const float* __restrict__ Ssum, const float* __restrict__ hid,
                        const float* __restrict__ w1, const float* __restrict__ b1,
                        const float* __restrict__ w3, const float* __restrict__ b3,
                        float* __restrict__ h1_out, float* __restrict__ logit_out,
                        float* __restrict__ out_logits, int slot,
                        float* __restrict__ out_hidden) {
  __shared__ float xgs[4][64];
  __shared__ float h1s[4][16];
  int t = threadIdx.x;                             // 64 threads
  for (int i = t; i < 256; i += 64)
    xgs[i >> 6][i & 63] = Ssum[i] * (1.f / 65536.f);
  __syncthreads();
  {
    int b = t >> 4, j = t & 15;
    float a = b1[j];
    for (int c = 0; c < 64; ++c) a += w1[j * 80 + c] * xgs[b][c];
    for (int k = 0; k < 16; ++k) a += w1[j * 80 + 64 + k] * hid[b * 16 + k];
    float g = 0.5f * a * (1.f + erff(a * 0.70710678f));   // exact gelu
    h1s[b][j] = g;
    h1_out[b * 16 + j] = g;
    if (out_hidden) out_hidden[b * 16 + j] = g;
  }
  __syncthreads();
  if (t < 12) {
    int b = t / 3, e = t % 3;
    float a = b3[e];
    for (int j = 0; j < 16; ++j) a += w3[e * 16 + j] * h1s[b][j];
    a = fmaxf(a, 0.f);
    logit_out[b * 3 + e] = a;
    out_logits[b * 6 + e * 2 + slot] = a;
  }
}

// ---------------- per (b,expert): softmax(q̂·k̂·temp) -> Weff = P @ Wv ----------------
__global__ void k_expw(const float* __restrict__ M, const float* __restrict__ qkv,
                       const float* __restrict__ temp, float* __restrict__ Weff) {
  int b = blockIdx.x / 3, e = blockIdx.x % 3;
  __shared__ float Ms[64][64];
  __shared__ float TQ[64][64];
  __shared__ float TK[64][64];
  __shared__ float P[64][4];
  __shared__ float nq[64], nk[64];
  const float* W = qkv + e * 12288;
  for (int idx = threadIdx.x; idx < 4096; idx += 256)
    Ms[idx >> 6][idx & 63] = M[b * 4096 + idx];
  __syncthreads();
  {
    int r = threadIdx.x >> 2;
    int v0 = (threadIdx.x & 3) << 4;
    float aq[16] = {}, ak[16] = {};
    for (int u = 0; u < 64; ++u) {
      float wq = W[r * 64 + u];
      float wk = W[(64 + r) * 64 + u];
      #pragma unroll
      for (int i = 0; i < 16; ++i) {
        float m = Ms[u][v0 + i];
        aq[i] += wq * m; ak[i] += wk * m;
      }
    }
    #pragma unroll
    for (int i = 0; i < 16; ++i) { TQ[r][v0 + i] = aq[i]; TK[r][v0 + i] = ak[i]; }
  }
  __syncthreads();
  if (threadIdx.x < 64) {
    int c = threadIdx.x;
    float sq = 0.f, sk = 0.f;
    for (int v = 0; v < 64; ++v) {
      sq += TQ[c][v] * W[c * 64 + v];
      sk += TK[c][v] * W[(64 + c) * 64 + v];
    }
    nq[c] = fmaxf(sqrtf(fmaxf(sq, 0.f)), 1e-12f);
    nk[c] = fmaxf(sqrtf(fmaxf(sk, 0.f)), 1e-12f);
  }
  __syncthreads();
  if (threadIdx.x < 64) {
    int rr = threadIdx.x, h = rr >> 2;
    float tp = temp[e * 16 + h];
    float s[4];
    #pragma unroll
    for (int d = 0; d < 4; ++d) {
      int kc = h * 4 + d;
      float g = 0.f;
      for (int v = 0; v < 64; ++v) g += TQ[rr][v] * W[(64 + kc) * 64 + v];
      s[d] = g / (nq[rr] * nk[kc]) * tp;
    }
    float mx = fmaxf(fmaxf(s[0], s[1]), fmaxf(s[2], s[3]));
    float es[4], sum = 0.f;
    #pragma unroll
    for (int d = 0; d < 4; ++d) { es[d] = __expf(s[d] - mx); sum += es[d]; }
    float inv = 1.f / sum;
    #pragma unroll
    for (int d = 0; d < 4; ++d) P[rr][d] = es[d] * inv;
  }
  __syncthreads();
  if (threadIdx.x < 64) {
    int rr = threadIdx.x, h = rr >> 2;
    for (int u = 0; u < 64; ++u) {
      float a = 0.f;
      #pragma unroll
      for (int d = 0; d < 4; ++d)
        a += P[rr][d] * W[(128 + h * 4 + d) * 64 + u];
      Weff[(size_t)(b * 3 + e) * 4096 + rr * 64 + u] = a;
    }
  }
}

// ------ Ktb[b][tap][o][u] = bf16( Σ_e l1_e Proj_e[o,c] dw_e[c,tap] Weff_e[c,u] ) ------
__global__ void k_kmat(const float* __restrict__ Weff, const float* __restrict__ dw,
                       const float* __restrict__ proj, const float* __restrict__ l1,
                       unsigned short* __restrict__ Ktb) {
  int b = blockIdx.x / 9, t = blockIdx.x % 9;
  __shared__ float S[64][68];
  __shared__ float Pr[64][68];
  int u = threadIdx.x >> 2, o0 = (threadIdx.x & 3) << 4;
  float acc[16] = {};
  for (int e = 0; e < 3; ++e) {
    __syncthreads();
    float le = l1[b * 3 + e];
    for (int idx = threadIdx.x; idx < 4096; idx += 256) {
      int c = idx >> 6, uu = idx & 63;
      S[c][uu] = le * dw[(e * 64 + c) * 9 + t] *
                 Weff[(size_t)(b * 3 + e) * 4096 + c * 64 + uu];
      Pr[c][uu] = proj[e * 4096 + uu * 64 + c];
    }
    __syncthreads();
    for (int c = 0; c < 64; ++c) {
      float sv = S[c][u];
      #pragma unroll
      for (int i = 0; i < 16; ++i) acc[i] += Pr[c][o0 + i] * sv;
    }
  }
  #pragma unroll
  for (int i = 0; i < 16; ++i)
    Ktb[(size_t)(b * 9 + t) * 4096 + (o0 + i) * 64 + u] = f2bs(acc[i]);
}

// -------- MFMA conv + residual + fused LN2 stats + xg2 sums --------
__global__ __launch_bounds__(256, 3)
void k_conv(const float* __restrict__ x, const float* __restrict__ mu,
            const float* __restrict__ rs, const float* __restrict__ lw,
            const float* __restrict__ lb, const unsigned short* __restrict__ Ktb,
            const float* __restrict__ beta, float* __restrict__ out1,
            const float* __restrict__ lw2, const float* __restrict__ lb2,
            float* __restrict__ mu2, float* __restrict__ rs2,
            float* __restrict__ Ssum2) {
  __shared__ __align__(16) short lds[20736];     // halo, then result [o][260]
  __shared__ float wred[4][64];

  int x0 = blockIdx.x << 4, y0 = blockIdx.y << 4, b = blockIdx.z;

  for (int idx = threadIdx.x; idx < 20736; idx += 256) {
    int c = idx / 324, hpix = idx - c * 324;
    int hy = hpix / 18, hx = hpix - hy * 18;
    int gy = y0 + hy - 1, gx = x0 + hx - 1;
    float v = 0.f;
    if ((unsigned)gy < 256u && (unsigned)gx < 256u) {
      int n = (gy << 8) + gx;
      float xv = x[((size_t)(b * 64 + c) << 16) + n];
      v = (xv - mu[(b << 16) + n]) * rs[(b << 16) + n] * lw[c] + lb[c];
    }
    lds[hpix * 64 + ((((c >> 3) ^ (hpix & 7)) << 3) | (c & 7))] = (short)f2bs(v);
  }
  __syncthreads();

  int w = threadIdx.x >> 6, l = threadIdx.x & 63;
  int l15 = l & 15, g = l >> 4;

  f32x4 acc[4][4] = {};
  const unsigned short* Kb = Ktb + (size_t)b * 9 * 4096;

  #pragma unroll 1
  for (int tap = 0; tap < 9; ++tap) {
    int ky = tap / 3, kx = tap - ky * 3;
    const unsigned short* Kt = Kb + (tap << 12);
    #pragma unroll
    for (int ks = 0; ks < 2; ++ks) {
      short8 bfr[4];
      #pragma unroll
      for (int ot = 0; ot < 4; ++ot)
        bfr[ot] = *(const short8*)(Kt + (((ot << 4) + l15) << 6) + (ks << 5) + (g << 3));
      int blk = ((ks << 2) | g);
      #pragma unroll
      for (int mi = 0; mi < 4; ++mi) {
        int hpix = ((w << 2) + mi + ky) * 18 + l15 + kx;
        short8 af = *(const short8*)(lds + hpix * 64 + ((blk ^ (hpix & 7)) << 3));
        #pragma unroll
        for (int ot = 0; ot < 4; ++ot)
          acc[mi][ot] = __builtin_amdgcn_mfma_f32_16x16x32_bf16(af, bfr[ot], acc[mi][ot], 0, 0, 0);
      }
    }
  }

  __syncthreads();                               // reuse lds as Rs[o][260]
  #pragma unroll
  for (int mi = 0; mi < 4; ++mi) {
    int p0 = (((w << 2) + mi) << 4) + (g << 2);
    #pragma unroll
    for (int ot = 0; ot < 4; ++ot) {
      int o = (ot << 4) + l15;
      short4 pk;
      pk.x = (short)f2bs(acc[mi][ot][0]);
      pk.y = (short)f2bs(acc[mi][ot][1]);
      pk.z = (short)f2bs(acc[mi][ot][2]);
      pk.w = (short)f2bs(acc[mi][ot][3]);
      *(short4*)(lds + o * 260 + p0) = pk;
    }
  }
  __syncthreads();

  // residual + store + LN2 stats (thread owns pixel p2)
  int p2 = threadIdx.x;
  int n = ((y0 + (p2 >> 4)) << 8) + x0 + (p2 & 15);
  float s = 0.f, s2 = 0.f;
  #pragma unroll
  for (int c = 0; c < 64; ++c) {
    size_t gi = ((size_t)(b * 64 + c) << 16) + n;
    float v = s2f(lds[c * 260 + p2]) + beta[c] * x[gi];
    out1[gi] = v;
    s += v; s2 += v * v;
    lds[c * 260 + p2] = (short)f2bs(v);          // own column only
  }
  float m = s * 0.015625f;
  float var = s2 * 0.015625f - m * m;
  float rstd = rsqrtf(var + 1e-5f);
  mu2[(b << 16) + n] = m;
  rs2[(b << 16) + n] = rstd;
  for (int c = 0; c < 64; ++c) {
    float lnv = (s2f(lds[c * 260 + p2]) - m) * rstd * lw2[c] + lb2[c];
    #pragma unroll
    for (int o = 32; o > 0; o >>= 1) lnv += __shfl_down(lnv, o, 64);
    if (l == 0) wred[w][c] = lnv;
  }
  __syncthreads();
  if (threadIdx.x < 64)
    atomicAdd(&Ssum2[b * 64 + threadIdx.x],
              wred[0][threadIdx.x] + wred[1][threadIdx.x] +
              wred[2][threadIdx.x] + wred[3][threadIdx.x]);
}

// ---------------- prep MLP weights as bf16: w1b[jt][c], w2b[o][jt], b1f[jt] ----------------
__global__ void k_prep(const float* __restrict__ w1_0, const float* __restrict__ w1_1,
                       const float* __restrict__ w1_2,
                       const float* __restrict__ b1_0, const float* __restrict__ b1_1,
                       const float* __restrict__ b1_2,
                       const float* __restrict__ w2_0, const float* __restrict__ w2_1,
                       const float* __restrict__ w2_2,
                       unsigned short* __restrict__ w1b, unsigned short* __restrict__ w2b,
                       float* __restrict__ b1f) {
  int idx = blockIdx.x * 256 + threadIdx.x;
  if (idx >= 448 * 64) return;
  int jt = idx >> 6, c = idx & 63;
  int e, j;
  if (jt < 64)       { e = 0; j = jt; }
  else if (jt < 192) { e = 1; j = jt - 64; }
  else               { e = 2; j = jt - 192; }
  const float* w1 = e == 0 ? w1_0 : (e == 1 ? w1_1 : w1_2);
  const float* w2 = e == 0 ? w2_0 : (e == 1 ? w2_1 : w2_2);
  int hf = 64 << e;
  w1b[jt * 64 + c]  = f2bs(w1[j * 64 + c]);
  w2b[c * 448 + jt] = f2bs(w2[c * hf + j]);
  if (c == 0) {
    const float* b1 = e == 0 ? b1_0 : (e == 1 ? b1_1 : b1_2);
    b1f[jt] = b1[j];
  }
}

// ---------------- MFMA fused MLP bank, LDS-free, all-register H ----------------
// 256 thr (4 waves), 128 px/block, 32 px/wave. xf B-frags loaded per-lane from
// global (64-B segments); epilogue is a direct float4 RMW on io. No barriers.
__global__ __launch_bounds__(256, 3)
void k_mlp(float* io,
           const float* __restrict__ mu2, const float* __restrict__ rs2,
           const float* __restrict__ lw, const float* __restrict__ lb,
           const unsigned short* __restrict__ w1b, const unsigned short* __restrict__ w2b,
           const float* __restrict__ b1f,
           const float* __restrict__ b2_0, const float* __restrict__ b2_1,
           const float* __restrict__ b2_2,
           const float* __restrict__ gamma, const float* __restrict__ l2) {
  int b  = blockIdx.x >> 9;
  int n0 = (blockIdx.x & 511) << 7;
  int t  = threadIdx.x;
  int w  = t >> 6, l = t & 63;
  int l15 = l & 15, g = l >> 4;

  size_t iob = ((size_t)b << 22) + n0;
  float l2v0 = l2[b * 3], l2v1 = l2[b * 3 + 1], l2v2 = l2[b * 3 + 2];

  // X B-frags (col = pixel l15, k = channel 8g+i), LN applied; 2 pixel-frags/wave
  short8 xf[2][2];
  #pragma unroll
  for (int pf = 0; pf < 2; ++pf) {
    int pl = (w << 5) + (pf << 4) + l15;
    float muv = mu2[(b << 16) + n0 + pl];
    float rsv = rs2[(b << 16) + n0 + pl];
    #pragma unroll
    for (int ks = 0; ks < 2; ++ks)
      #pragma unroll
      for (int i = 0; i < 8; ++i) {
        int c = (ks << 5) + (g << 3) + i;
        float v = (io[iob + ((size_t)c << 16) + pl] - muv) * rsv * lw[c] + lb[c];
        xf[pf][ks][i] = (short)f2bs(v);
      }
  }

  int jrow = ((l15 >> 2) << 3) + (l15 & 3);      // permuted W1 row for this lane

  f32x4 acc2[2][4] = {{{0,0,0,0},{0,0,0,0},{0,0,0,0},{0,0,0,0}},
                      {{0,0,0,0},{0,0,0,0},{0,0,0,0},{0,0,0,0}}};

  #pragma unroll 2
  for (int jb = 0; jb < 14; ++jb) {              // 32 j per iteration
    int j0 = jb << 5;
    float le = (jb < 2) ? l2v0 : (jb < 6 ? l2v1 : l2v2);
    short8 w1a[2][2];
    f32x4 b1v[2];
    #pragma unroll
    for (int q = 0; q < 2; ++q) {
      int jt = j0 + jrow + (q << 2);
      w1a[q][0] = *(const short8*)(w1b + (jt << 6) + (g << 3));
      w1a[q][1] = *(const short8*)(w1b + (jt << 6) + 32 + (g << 3));
      b1v[q] = *(const f32x4*)(b1f + j0 + (g << 3) + (q << 2));
    }
    short8 A2[2];
    #pragma unroll
    for (int pf = 0; pf < 2; ++pf) {
      #pragma unroll
      for (int q = 0; q < 2; ++q) {
        f32x4 d1 = {0.f, 0.f, 0.f, 0.f};
        d1 = __builtin_amdgcn_mfma_f32_16x16x32_bf16(w1a[q][0], xf[pf][0], d1, 0, 0, 0);
        d1 = __builtin_amdgcn_mfma_f32_16x16x32_bf16(w1a[q][1], xf[pf][1], d1, 0, 0, 0);
        #pragma unroll
        for (int r = 0; r < 4; ++r) {            // lane holds j = j0 + 8g + 4q + r
          float tv = d1[r] + b1v[q][r];
          float uu = tv * (0.7978845608f + 0.0356774081f * tv * tv);
          float gv = le * __fdividef(tv, 1.f + __expf(-2.f * uu));  // tanh-gelu
          A2[pf][(q << 2) + r] = (short)f2bs(gv);
        }
      }
    }
    #pragma unroll
    for (int ot = 0; ot < 4; ++ot) {
      short8 w2f = *(const short8*)(w2b + (((ot << 4) + l15) * 448) + j0 + (g << 3));
      acc2[0][ot] = __builtin_amdgcn_mfma_f32_16x16x32_bf16(A2[0], w2f, acc2[0][ot], 0, 0, 0);
      acc2[1][ot] = __builtin_amdgcn_mfma_f32_16x16x32_bf16(A2[1], w2f, acc2[1][ot], 0, 0, 0);
    }
  }

  // epilogue: direct global RMW, float4 per (pf, ot); rows p = 4g..4g+3
  #pragma unroll
  for (int ot = 0; ot < 4; ++ot) {
    int o = (ot << 4) + l15;
    float bias = l2v0 * b2_0[o] + l2v1 * b2_1[o] + l2v2 * b2_2[o];
    float gmv = gamma[o];
    #pragma unroll
    for (int pf = 0; pf < 2; ++pf) {
      int p0 = (w << 5) + (pf << 4) + (g << 2);
      float* gp = io + iob + ((size_t)o << 16) + p0;
      f32x4 old = *(const f32x4*)gp;
      f32x4 res;
      #pragma unroll
      for (int r = 0; r < 4; ++r)
        res[r] = acc2[pf][ot][r] + gmv * old[r] + bias;
      *(f32x4*)gp = res;
    }
  }
}

extern "C" void kernel_launch(void* const* d_in, const int* in_sizes, int n_in,
                              void* d_out, int out_size, void* d_ws, size_t ws_size,
                              hipStream_t stream) {
  (void)in_sizes; (void)n_in; (void)out_size; (void)ws_size;
  const float* x        = (const float*)d_in[0];
  const float* hidden   = (const float*)d_in[1];
  const float* ln1_w    = (const float*)d_in[2];
  const float* ln1_b    = (const float*)d_in[3];
  const float* ln2_w    = (const float*)d_in[4];
  const float* ln2_b    = (const float*)d_in[5];
  const float* beta     = (const float*)d_in[6];
  const float* gamma    = (const float*)d_in[7];
  const float* att_temp = (const float*)d_in[8];
  const float* att_qkv  = (const float*)d_in[9];
  const float* att_dw   = (const float*)d_in[10];
  const float* att_proj = (const float*)d_in[11];
  const float* ar1_w    = (const float*)d_in[12];
  const float* ar1_b    = (const float*)d_in[13];
  const float* ar3_w    = (const float*)d_in[14];
  const float* ar3_b    = (const float*)d_in[15];
  const float* mr1_w    = (const float*)d_in[16];
  const float* mr1_b    = (const float*)d_in[17];
  const float* mr3_w    = (const float*)d_in[18];
  const float* mr3_b    = (const float*)d_in[19];
  const float* w1s[3] = {(const float*)d_in[20], (const float*)d_in[24], (const float*)d_in[28]};
  const float* b1s[3] = {(const float*)d_in[21], (const float*)d_in[25], (const float*)d_in[29]};
  const float* w2s[3] = {(const float*)d_in[22], (const float*)d_in[26], (const float*)d_in[30]};
  const float* b2s[3] = {(const float*)d_in[23], (const float*)d_in[27], (const float*)d_in[31]};

  // ---- workspace (~4.9 MB fp32) ----
  float* F    = (float*)d_ws;
  float* mu1  = F + 0;          // 262144
  float* rs1  = F + 262144;     // 262144
  float* mu2  = F + 524288;     // 262144
  float* rs2  = F + 786432;     // 262144
  float* M    = F + 1048576;    // 16384 ┐
  float* xg1s = F + 1064960;    // 256   ├ zeroed together (16896)
  float* xg2s = F + 1065216;    // 256   ┘
  float* h1a  = F + 1065472;    // 64
  float* h1m  = F + 1065536;    // 64
  float* l1   = F + 1065600;    // 16
  float* l2   = F + 1065616;    // 16
  float* Weff = F + 1065632;    // 49152
  unsigned short* Ktb = (unsigned short*)(F + 1114784);  // 147456 ushorts
  float* b1f  = F + 1188512;    // 448
  unsigned short* w1b = (unsigned short*)(F + 1188960);  // 28672 ushorts
  unsigned short* w2b = (unsigned short*)(F + 1203296);  // 28672 ushorts

  float* out_main   = (float*)d_out;             // holds out1 between banks
  float* out_hidden = out_main + 16777216;
  float* out_logits = out_main + 16777280;

  // ---- attention bank ----
  k_zero   <<<66, 256, 0, stream>>>(M, 16896);   // M + xg1s + xg2s
  k_statsxg<<<1024, 256, 0, stream>>>(x, mu1, rs1, ln1_w, ln1_b, xg1s, M);
  k_route  <<<1, 64, 0, stream>>>(xg1s, hidden, ar1_w, ar1_b, ar3_w, ar3_b,
                                  h1a, l1, out_logits, 0, nullptr);
  k_expw   <<<12, 256, 0, stream>>>(M, att_qkv, att_temp, Weff);
  k_kmat   <<<36, 256, 0, stream>>>(Weff, att_dw, att_proj, l1, Ktb);
  k_conv   <<<dim3(16, 16, 4), 256, 0, stream>>>(x, mu1, rs1, ln1_w, ln1_b, Ktb,
                                                 beta, out_main, ln2_w, ln2_b,
                                                 mu2, rs2, xg2s);
  // ---- MLP bank (out1 lives in d_out) ----
  k_route  <<<1, 64, 0, stream>>>(xg2s, h1a, mr1_w, mr1_b, mr3_w, mr3_b,
                                  h1m, l2, out_logits, 1, out_hidden);
  k_prep   <<<112, 256, 0, stream>>>(w1s[0], w1s[1], w1s[2], b1s[0], b1s[1], b1s[2],
                                     w2s[0], w2s[1], w2s[2], w1b, w2b, b1f);
  k_mlp    <<<2048, 256, 0, stream>>>(out_main, mu2, rs2, ln2_w, ln2_b,
                                      w1b, w2b, b1f, b2s[0], b2s[1], b2s[2],
                                      gamma, l2);
}